// Round 20
// baseline (704.470 us; speedup 1.0000x reference)
//
#include <hip/hip_runtime.h>
#include <hip/hip_bf16.h>

typedef __bf16 bf16_t;
typedef __bf16 bf16x8 __attribute__((ext_vector_type(8)));
typedef __bf16 bf16x4 __attribute__((ext_vector_type(4)));
typedef float  f32x4  __attribute__((ext_vector_type(4)));

#define BN_   16384
#define DIN_  128
#define DEM_  64
#define DH_   400
#define DHP_  416   // K padded to 32-multiple
#define DHA_  512   // N padded to 128-tile coverage
#define GH_   256
#define MM_   4
#define EPS_  1e-5f
#define PCOLS 448   // partial-stats column stride
#define NCH   128   // partial-stats chunks (GEMM-fused layout)
#define NCHMI 256   // partial-stats chunks (k_mix-fused layout)

// -------- fused dtype detector + MFMA C/D layout probe (one dispatch) --------
__global__ __launch_bounds__(256) void k_detect_probe(const unsigned* __restrict__ w,
                                                      int* __restrict__ flag,
                                                      int* __restrict__ layC)
{
  __shared__ int cnt[256];
  int c = 0;
  for (int i = 0; i < 16; ++i) {
    unsigned v = w[threadIdx.x * 16 + i];
    float lo = __uint_as_float((v & 0xffffu) << 16);
    if (!(fabsf(lo) < 1e4f)) ++c;
  }
  cnt[threadIdx.x] = c;
  __syncthreads();
  if (threadIdx.x == 0) {
    int t = 0;
    for (int i = 0; i < 256; ++i) t += cnt[i];
    flag[0] = (t > 64) ? 1 : 0;     // 1 = inputs are float32
  }
  if (threadIdx.x < 64) {
    int l = threadIdx.x;
    bf16x8 av, bv;
#pragma unroll
    for (int e = 0; e < 8; ++e) { av[e] = (bf16_t)0.f; bv[e] = (bf16_t)0.f; }
    if ((l >> 4) == 0) av[0] = (bf16_t)(float)(l & 15);
    if (l == 0)        bv[0] = (bf16_t)1.f;
    f32x4 acc = {0.f, 0.f, 0.f, 0.f};
    acc = __builtin_amdgcn_mfma_f32_16x16x32_bf16(av, bv, acc, 0, 0, 0);
    if (l == 1) layC[0] = (acc[0] > 0.5f) ? 1 : 0;
  }
}

#define NS_ 26
struct SmallTab {
  const void* src[NS_];
  bf16_t*     dst[NS_];
  int         n[NS_];
};

struct Cvt2 {
  const void* src1; bf16_t* dst1; int n1;
  const void* src2; bf16_t* dst2; int n2;
};

// -------- merged front/gate transposes + small converts + big converts -------
// z < NT_  : transpose tensor z (reads RAW d_in with dtype flag)
// z == NT_ : small-tensor conversions (flat block id over 7x8 grid)
// z >  NT_ : x/emb conversion slices (8 slices x 56 blocks, grid-stride)
#define NT_ 9
#define CVZ 8
struct TransTab {
  const void* src[NT_];
  bf16_t*     dst[NT_];
  int K[NT_], N[NT_], KP[NT_], NPa[NT_], usef[NT_];
};

__global__ __launch_bounds__(256) void k_transAll(TransTab tt, SmallTab st, Cvt2 cv,
                                                  const int* __restrict__ flag)
{
  __shared__ float T[64][65];
  const int z = blockIdx.z;
  if (z > NT_) {
    const int f = flag[0];
    const int slice = z - NT_ - 1;                        // 0..CVZ-1
    const int flat = slice * 56 + blockIdx.y * 7 + blockIdx.x;
    const int total = cv.n1 + cv.n2;
    for (int i = flat * 256 + threadIdx.x; i < total; i += 56 * CVZ * 256) {
      if (i < cv.n1)
        cv.dst1[i] = f ? (bf16_t)((const float*)cv.src1)[i] : ((const bf16_t*)cv.src1)[i];
      else {
        int j = i - cv.n1;
        cv.dst2[j] = f ? (bf16_t)((const float*)cv.src2)[j] : ((const bf16_t*)cv.src2)[j];
      }
    }
    return;
  }
  if (z == NT_) {
    const int f = flag[0];
    const int flat = blockIdx.y * 7 + blockIdx.x;
    if (flat >= NS_) return;
    const void* s = st.src[flat];
    bf16_t*     d = st.dst[flat];
    const int   n = st.n[flat];
    for (int i = threadIdx.x; i < n; i += 256)
      d[i] = f ? (bf16_t)((const float*)s)[i] : ((const bf16_t*)s)[i];
    return;
  }
  const int K = tt.K[z], N = tt.N[z], KP = tt.KP[z], NPa = tt.NPa[z];
  const int k0 = blockIdx.x * 64, n0 = blockIdx.y * 64;
  if (k0 >= KP || n0 >= NPa) return;
  const int f = tt.usef[z] ? flag[0] : 0;
  const float*  sf = (const float*) tt.src[z];
  const bf16_t* sb = (const bf16_t*)tt.src[z];
  bf16_t* dp = tt.dst[z];
  const int lr = threadIdx.x >> 6, ln = threadIdx.x & 63;
#pragma unroll
  for (int p = 0; p < 16; ++p) {
    int kl = p * 4 + lr;
    int k = k0 + kl, n = n0 + ln;
    float v = 0.f;
    if (k < K && n < N)
      v = f ? sf[(size_t)k * N + n] : (float)sb[(size_t)k * N + n];
    T[kl][ln] = v;
  }
  __syncthreads();
#pragma unroll
  for (int p = 0; p < 16; ++p) {
    int nl = p * 4 + lr;
    int n = n0 + nl, k = k0 + ln;
    if (n < NPa && k < KP) dp[(size_t)n * KP + k] = (bf16_t)T[ln][nl];
  }
}

// ---- merged per-layer module-weight prep: INLINE BN-stats + scaled transpose
//      + bias fold.  grid (7, 9, 4): y<8 -> transpose tile; y==8 -> foldB.
__global__ __launch_bounds__(256) void k_prepW(
    const void* __restrict__ modW, size_t off, const bf16_t* __restrict__ modb,
    const float* __restrict__ ps, const float* __restrict__ pq, int nch, int per_m,
    const bf16_t* __restrict__ g, const bf16_t* __restrict__ b,
    bf16_t* __restrict__ WtM, float* __restrict__ bM,
    const int* __restrict__ flag)
{
  __shared__ float T[64][65];
  __shared__ float sK[64];
  __shared__ float tK[400];
  const int f = flag[0];
  const int m = blockIdx.z;
  const int mm = per_m ? m : 0;
  const int tid = threadIdx.x;
  if (blockIdx.y == 8) {
    // inline BN shift for all k, then fold bias
    for (int k = tid; k < DH_; k += 256) {
      float S = 0.f, Q = 0.f;
      for (int ch = 0; ch < nch; ++ch) {
        size_t idx = ((size_t)ch * MM_ + mm) * PCOLS + k;
        S += ps[idx]; Q += pq[idx];
      }
      float mean = S * (1.f / BN_);
      float var  = fmaxf(Q * (1.f / BN_) - mean * mean, 0.f);
      float rstd = rsqrtf(var + EPS_);
      float s = (float)g[m * DH_ + k] * rstd;
      tK[k] = (float)b[m * DH_ + k] - mean * s;
    }
    __syncthreads();
    float* ls = &T[0][0];
    const int ncg = blockIdx.x;
    const int n = ncg * 64 + (tid & 63);
    const int ks = tid >> 6;
    float a = 0.f;
    if (n < DH_) {
      for (int k = ks * 100; k < ks * 100 + 100; ++k) {
        size_t idx = off + ((size_t)m * DH_ + k) * DH_ + n;
        float wv = f ? ((const float*)modW)[idx] : (float)((const bf16_t*)modW)[idx];
        a += tK[k] * wv;
      }
    }
    ls[tid] = a;
    __syncthreads();
    if (tid < 64) {
      int nn = ncg * 64 + tid;
      float v = ls[tid] + ls[tid + 64] + ls[tid + 128] + ls[tid + 192];
      if (nn < DH_) v += (float)modb[m * DH_ + nn];
      else v = 0.f;
      bM[m * DHA_ + nn] = v;
    }
    if (ncg == 6 && tid < 64) bM[m * DHA_ + 448 + tid] = 0.f;
    return;
  }
  // transpose tile: inline BN scale for this tile's 64 k values
  {
    const int kl = tid & 63, sub = tid >> 6;     // 4 chunk-subsets
    const int k = blockIdx.x * 64 + kl;
    float S = 0.f, Q = 0.f;
    if (k < DH_) {
      for (int ch = sub; ch < nch; ch += 4) {
        size_t idx = ((size_t)ch * MM_ + mm) * PCOLS + k;
        S += ps[idx]; Q += pq[idx];
      }
    }
    float* red = &T[0][0];                       // 512 floats scratch
    red[sub * 64 + kl] = S;
    red[256 + sub * 64 + kl] = Q;
    __syncthreads();
    if (tid < 64) {
      float St = red[tid] + red[64 + tid] + red[128 + tid] + red[192 + tid];
      float Qt = red[256 + tid] + red[320 + tid] + red[384 + tid] + red[448 + tid];
      float s = 0.f;
      int k2 = blockIdx.x * 64 + tid;
      if (k2 < DH_) {
        float mean = St * (1.f / BN_);
        float var  = fmaxf(Qt * (1.f / BN_) - mean * mean, 0.f);
        float rstd = rsqrtf(var + EPS_);
        s = (float)g[m * DH_ + k2] * rstd;
      }
      sK[tid] = s;
    }
    __syncthreads();
  }
  const float*  sf = (const float*) modW + off + (size_t)m * DH_ * DH_;
  const bf16_t* sb = (const bf16_t*)modW + off + (size_t)m * DH_ * DH_;
  bf16_t* dp = WtM + (size_t)m * DHA_ * DHP_;
  const int k0 = blockIdx.x * 64, n0 = blockIdx.y * 64;
  const int lr = threadIdx.x >> 6, ln = threadIdx.x & 63;
#pragma unroll
  for (int p = 0; p < 16; ++p) {
    int kl = p * 4 + lr;
    int k = k0 + kl, n = n0 + ln;
    float v = 0.f;
    if (k < DH_ && n < DH_)
      v = f ? sf[(size_t)k * DH_ + n] : (float)sb[(size_t)k * DH_ + n];
    if (k < DH_) v *= sK[kl];
    T[kl][ln] = v;
  }
  __syncthreads();
#pragma unroll
  for (int p = 0; p < 16; ++p) {
    int nl = p * 4 + lr;
    int n = n0 + nl, k = k0 + ln;
    if (n < DHA_ && k < DHP_) dp[(size_t)n * DHP_ + k] = (bf16_t)T[ln][nl];
  }
}

// ------------------------- staged GEMM core (m97 structure + T2 swizzle) -----
__device__ __forceinline__ void gload_lds16(const bf16_t* g, bf16_t* l) {
#if __has_builtin(__builtin_amdgcn_global_load_lds)
  __builtin_amdgcn_global_load_lds((const __attribute__((address_space(1))) void*)g,
                                   (__attribute__((address_space(3))) void*)l, 16, 0, 0);
#else
  *(bf16x8*)l = *(const bf16x8*)g;
#endif
}

__device__ __forceinline__ void stage128x32(const bf16_t* __restrict__ g, int ld,
                                            bf16_t* lds, int t) {
  const int c1 = t + 256;
  const int q0 = ((t  & 3) ^ ((t  >> 3) & 3)) * 8;
  const int q1 = ((c1 & 3) ^ ((c1 >> 3) & 3)) * 8;
  gload_lds16(g + (size_t)(t  >> 2) * ld + q0, lds + t  * 8);
  gload_lds16(g + (size_t)(c1 >> 2) * ld + q1, lds + c1 * 8);
}

__device__ __forceinline__ void acc_zero(f32x4 (&acc)[4][4]) {
  const f32x4 z = {0.f, 0.f, 0.f, 0.f};
#pragma unroll
  for (int i = 0; i < 4; ++i)
#pragma unroll
    for (int j = 0; j < 4; ++j) acc[i][j] = z;
}

// single-barrier double-buffer; trailing barrier frees staging LDS for epilogue
template<int KS>
__device__ __forceinline__ void gemm_staged(
    const bf16_t* __restrict__ ga, int lda,
    const bf16_t* __restrict__ gb, int ldb,
    bf16_t* ldsA, bf16_t* ldsB,
    int wr, int wc, int rr, int qq, int t,
    f32x4 (&acc)[4][4])
{
  const int qs = (qq ^ ((rr >> 1) & 3)) * 8;
  stage128x32(ga, lda, ldsA, t);
  stage128x32(gb, ldb, ldsB, t);
  int cur = 0;
#pragma unroll 1
  for (int ks = 0; ks < KS; ++ks) {
    __syncthreads();
    if (ks + 1 < KS) {
      stage128x32(ga + (ks + 1) * 32, lda, ldsA + (cur ^ 1) * 4096, t);
      stage128x32(gb + (ks + 1) * 32, ldb, ldsB + (cur ^ 1) * 4096, t);
    }
    const bf16_t* la = ldsA + cur * 4096;
    const bf16_t* lb = ldsB + cur * 4096;
    bf16x8 av[4], bv[4];
#pragma unroll
    for (int i = 0; i < 4; ++i)
      av[i] = *reinterpret_cast<const bf16x8*>(la + (wr + i * 16 + rr) * 32 + qs);
#pragma unroll
    for (int i = 0; i < 4; ++i)
      bv[i] = *reinterpret_cast<const bf16x8*>(lb + (wc + i * 16 + rr) * 32 + qs);
#pragma unroll
    for (int i = 0; i < 4; ++i)
#pragma unroll
      for (int j = 0; j < 4; ++j)
        acc[i][j] = __builtin_amdgcn_mfma_f32_16x16x32_bf16(av[i], bv[j], acc[i][j], 0, 0, 0);
    cur ^= 1;
  }
  __syncthreads();
}

// runtime-KS variant (for the merged front pair)
__device__ __forceinline__ void gemm_staged_rt(
    const bf16_t* __restrict__ ga, int lda,
    const bf16_t* __restrict__ gb, int ldb,
    bf16_t* ldsA, bf16_t* ldsB,
    int wr, int wc, int rr, int qq, int t, int KS,
    f32x4 (&acc)[4][4])
{
  const int qs = (qq ^ ((rr >> 1) & 3)) * 8;
  stage128x32(ga, lda, ldsA, t);
  stage128x32(gb, ldb, ldsB, t);
  int cur = 0;
#pragma unroll 1
  for (int ks = 0; ks < KS; ++ks) {
    __syncthreads();
    if (ks + 1 < KS) {
      stage128x32(ga + (ks + 1) * 32, lda, ldsA + (cur ^ 1) * 4096, t);
      stage128x32(gb + (ks + 1) * 32, ldb, ldsB + (cur ^ 1) * 4096, t);
    }
    const bf16_t* la = ldsA + cur * 4096;
    const bf16_t* lb = ldsB + cur * 4096;
    bf16x8 av[4], bv[4];
#pragma unroll
    for (int i = 0; i < 4; ++i)
      av[i] = *reinterpret_cast<const bf16x8*>(la + (wr + i * 16 + rr) * 32 + qs);
#pragma unroll
    for (int i = 0; i < 4; ++i)
      bv[i] = *reinterpret_cast<const bf16x8*>(lb + (wc + i * 16 + rr) * 32 + qs);
#pragma unroll
    for (int i = 0; i < 4; ++i)
#pragma unroll
      for (int j = 0; j < 4; ++j)
        acc[i][j] = __builtin_amdgcn_mfma_f32_16x16x32_bf16(av[i], bv[j], acc[i][j], 0, 0, 0);
    cur ^= 1;
  }
  __syncthreads();
}

// ------------------------------------------------- generic bias(+relu) GEMM
template<int KS, bool RELU, bool OUTF32>
__global__ __launch_bounds__(256, 4) void k_gemm_bias(
    const bf16_t* __restrict__ A, int lda,
    const bf16_t* __restrict__ Bt, int ldb,
    const bf16_t* __restrict__ bias, int nbias,
    void* __restrict__ outv, int ldo, int nout,
    const int* __restrict__ layC)
{
  __shared__ bf16_t sAB[4 * 4096];
  const int lay = layC[0];
  const int t = threadIdx.x;
  const int w = t >> 6, lane = t & 63;
  const int rr = lane & 15, qq = lane >> 4;
  const int wr = (w >> 1) * 64, wc = (w & 1) * 64;
  const int rowT = blockIdx.x * 128, colT = blockIdx.y * 128;
  f32x4 acc[4][4]; acc_zero(acc);
  gemm_staged<KS>(A + (size_t)rowT * lda, lda, Bt + (size_t)colT * ldb, ldb,
                  sAB, sAB + 8192, wr, wc, rr, qq, t, acc);
  const int row0 = rowT + wr, col0 = colT + wc;
  float bjv[4];
#pragma unroll
  for (int j = 0; j < 4; ++j) {
    int c = col0 + j * 16 + rr;
    bjv[j] = (c < nbias) ? (float)bias[c] : 0.f;
  }
  if (lay == 0 && !OUTF32) {
    bf16_t* eld = sAB + w * 2304;     // 32 rows x stride 72
#pragma unroll
    for (int p = 0; p < 2; ++p) {
#pragma unroll
      for (int ii = 0; ii < 2; ++ii) {
        int i = p * 2 + ii;
#pragma unroll
        for (int j = 0; j < 4; ++j) {
#pragma unroll
          for (int e = 0; e < 4; ++e) {
            float v = acc[i][j][e] + bjv[j];
            if (RELU) v = fmaxf(v, 0.f);
            eld[(ii * 16 + qq * 4 + e) * 72 + j * 16 + rr] = (bf16_t)v;
          }
        }
      }
#pragma unroll
      for (int rb = 0; rb < 4; ++rb) {
        int rl = rb * 8 + (lane >> 3);
        int c8 = (lane & 7) * 8;
        bf16x8 vv = *reinterpret_cast<const bf16x8*>(eld + rl * 72 + c8);
        int row = row0 + p * 32 + rl;
        int col = colT + wc + c8;
        if (col < nout)
          *reinterpret_cast<bf16x8*>((bf16_t*)outv + (size_t)row * ldo + col) = vv;
      }
    }
  } else {
#pragma unroll
    for (int j = 0; j < 4; ++j) {
#pragma unroll
      for (int i = 0; i < 4; ++i) {
#pragma unroll
        for (int e = 0; e < 4; ++e) {
          int ri = lay ? rr : qq * 4 + e;
          int ci = lay ? qq * 4 + e : rr;
          int row = row0 + i * 16 + ri;
          int col = col0 + j * 16 + ci;
          if (col >= nout) continue;
          float bv = (col < nbias) ? (float)bias[col] : 0.f;
          float v = acc[i][j][e] + bv;
          if (RELU) v = fmaxf(v, 0.f);
          if (OUTF32) ((float*)outv)[(size_t)row * ldo + col] = v;
          else ((bf16_t*)outv)[(size_t)row * ldo + col] = (bf16_t)v;
        }
      }
    }
  }
}

// ---- merged front pair: z=0: out1=relu(x@W1+b1)  z=1: emb0=emb@em_w+em_b ----
__global__ __launch_bounds__(256, 4) void k_gemm_front_pair(
    const bf16_t* __restrict__ A0, const bf16_t* __restrict__ A1,
    const bf16_t* __restrict__ B0, const bf16_t* __restrict__ B1,
    const bf16_t* __restrict__ bias0, const bf16_t* __restrict__ bias1,
    bf16_t* __restrict__ o0, bf16_t* __restrict__ o1,
    const int* __restrict__ layC)
{
  __shared__ bf16_t sAB[4 * 4096];
  const int z = blockIdx.z;
  const bf16_t* A    = z ? A1 : A0;
  const bf16_t* Bt   = z ? B1 : B0;
  const bf16_t* bias = z ? bias1 : bias0;
  bf16_t* outv       = z ? o1 : o0;
  const int  ld   = z ? DEM_ : DIN_;   // lda == ldb for both
  const int  KS   = z ? 2 : 4;
  const bool relu = (z == 0);
  const int lay = layC[0];
  const int t = threadIdx.x;
  const int w = t >> 6, lane = t & 63;
  const int rr = lane & 15, qq = lane >> 4;
  const int wr = (w >> 1) * 64, wc = (w & 1) * 64;
  const int rowT = blockIdx.x * 128, colT = blockIdx.y * 128;
  f32x4 acc[4][4]; acc_zero(acc);
  gemm_staged_rt(A + (size_t)rowT * ld, ld, Bt + (size_t)colT * ld, ld,
                 sAB, sAB + 8192, wr, wc, rr, qq, t, KS, acc);
  const int row0 = rowT + wr, col0 = colT + wc;
  float bjv[4];
#pragma unroll
  for (int j = 0; j < 4; ++j) {
    int c = col0 + j * 16 + rr;
    bjv[j] = (c < DH_) ? (float)bias[c] : 0.f;
  }
  if (lay == 0) {
    bf16_t* eld = sAB + w * 2304;
#pragma unroll
    for (int p = 0; p < 2; ++p) {
#pragma unroll
      for (int ii = 0; ii < 2; ++ii) {
        int i = p * 2 + ii;
#pragma unroll
        for (int j = 0; j < 4; ++j) {
#pragma unroll
          for (int e = 0; e < 4; ++e) {
            float v = acc[i][j][e] + bjv[j];
            if (relu) v = fmaxf(v, 0.f);
            eld[(ii * 16 + qq * 4 + e) * 72 + j * 16 + rr] = (bf16_t)v;
          }
        }
      }
#pragma unroll
      for (int rb = 0; rb < 4; ++rb) {
        int rl = rb * 8 + (lane >> 3);
        int c8 = (lane & 7) * 8;
        bf16x8 vv = *reinterpret_cast<const bf16x8*>(eld + rl * 72 + c8);
        int row = row0 + p * 32 + rl;
        int col = colT + wc + c8;
        if (col < DHP_)
          *reinterpret_cast<bf16x8*>(outv + (size_t)row * DHP_ + col) = vv;
      }
    }
  } else {
#pragma unroll
    for (int j = 0; j < 4; ++j) {
#pragma unroll
      for (int i = 0; i < 4; ++i) {
#pragma unroll
        for (int e = 0; e < 4; ++e) {
          int row = row0 + i * 16 + rr;
          int col = col0 + j * 16 + qq * 4 + e;
          if (col >= DHP_) continue;
          float bv = (col < DH_) ? (float)bias[col] : 0.f;
          float v = acc[i][j][e] + bv;
          if (relu) v = fmaxf(v, 0.f);
          outv[(size_t)row * DHP_ + col] = (bf16_t)v;
        }
      }
    }
  }
}

// ---- base layer 2: outA=relu(A@W2+b2); emb1=relu(emb0*(A@W2+b2)); fused stats
__global__ __launch_bounds__(256, 4) void k_gemm_base2(
    const bf16_t* __restrict__ A, const bf16_t* __restrict__ Bt,
    const bf16_t* __restrict__ bias, const bf16_t* __restrict__ emb0,
    bf16_t* __restrict__ outA, bf16_t* __restrict__ emb1,
    float* __restrict__ ps, float* __restrict__ pq,
    const int* __restrict__ layC)
{
  __shared__ bf16_t sAB[4 * 4096];
  __shared__ float rs[2][128], rq[2][128];
  const int lay = layC[0];
  const int t = threadIdx.x;
  const int w = t >> 6, lane = t & 63;
  const int rr = lane & 15, qq = lane >> 4;
  const int wr = (w >> 1) * 64, wc = (w & 1) * 64;
  const int rowT = blockIdx.x * 128, colT = blockIdx.y * 128;
  f32x4 acc[4][4]; acc_zero(acc);
  gemm_staged<13>(A + (size_t)rowT * DHP_, DHP_, Bt + (size_t)colT * DHP_, DHP_,
                  sAB, sAB + 8192, wr, wc, rr, qq, t, acc);
  const int row0 = rowT + wr, col0 = colT + wc;
  float bjv[4];
  bool cok[4];
#pragma unroll
  for (int j = 0; j < 4; ++j) {
    int c = col0 + j * 16 + rr;
    bjv[j] = (c < DH_) ? (float)bias[c] : 0.f;
    cok[j] = (c < DHP_);
  }
  float s[4] = {0.f, 0.f, 0.f, 0.f}, q[4] = {0.f, 0.f, 0.f, 0.f};
  if (lay == 0) {
#pragma unroll
    for (int j = 0; j < 4; ++j) {
      if (!cok[j]) continue;
#pragma unroll
      for (int i = 0; i < 4; ++i)
#pragma unroll
        for (int e = 0; e < 4; ++e) {
          float o = fmaxf(acc[i][j][e] + bjv[j], 0.f);
          s[j] += o; q[j] += o * o;
        }
    }
    float* fld = reinterpret_cast<float*>(sAB) + w * 1088;   // 16 rows x 68 f32
#pragma unroll
    for (int i = 0; i < 4; ++i) {
#pragma unroll
      for (int j = 0; j < 4; ++j)
#pragma unroll
        for (int e = 0; e < 4; ++e)
          fld[(qq * 4 + e) * 68 + j * 16 + rr] = acc[i][j][e] + bjv[j];
#pragma unroll
      for (int rb = 0; rb < 4; ++rb) {
        int rl = rb * 4 + (lane >> 4);
        int c4 = (lane & 15) * 4;
        f32x4 op4 = *reinterpret_cast<const f32x4*>(fld + rl * 68 + c4);
        int row = row0 + i * 16 + rl;
        int col = colT + wc + c4;
        if (col < DHP_) {
          bf16x4 e04 = *reinterpret_cast<const bf16x4*>(emb0 + (size_t)row * DHP_ + col);
          bf16x4 oA4, e14;
#pragma unroll
          for (int e = 0; e < 4; ++e) {
            float op = op4[e];
            oA4[e] = (bf16_t)fmaxf(op, 0.f);
            e14[e] = (bf16_t)fmaxf((float)e04[e] * op, 0.f);
          }
          *reinterpret_cast<bf16x4*>(outA + (size_t)row * DHP_ + col) = oA4;
          *reinterpret_cast<bf16x4*>(emb1 + (size_t)row * DHP_ + col) = e14;
        }
      }
    }
  } else {
#pragma unroll
    for (int j = 0; j < 4; ++j) {
#pragma unroll
      for (int i = 0; i < 4; ++i) {
#pragma unroll
        for (int e = 0; e < 4; ++e) {
          int ri = rr;
          int ci = qq * 4 + e;
          int row = row0 + i * 16 + ri;
          int col = col0 + j * 16 + ci;
          if (col >= DHP_) continue;
          float bv = (col < DH_) ? (float)bias[col] : 0.f;
          float op = acc[i][j][e] + bv;
          float o  = fmaxf(op, 0.f);
          float e0 = (float)emb0[(size_t)row * DHP_ + col];
          float m1 = fmaxf(e0 * op, 0.f);
          outA[(size_t)row * DHP_ + col] = (bf16_t)o;
          emb1[(size_t)row * DHP_ + col] = (bf16_t)m1;
        }
      }
    }
  }
#pragma unroll
  for (int j = 0; j < 4; ++j) {
    s[j] += __shfl_xor(s[j], 16); s[j] += __shfl_xor(s[j], 32);
    q[j] += __shfl_xor(q[j], 16); q[j] += __shfl_xor(q[j], 32);
  }
  if (lane < 16) {
#pragma unroll
    for (int j = 0; j < 4; ++j) {
      rs[w >> 1][(w & 1) * 64 + j * 16 + lane] = s[j];
      rq[w >> 1][(w & 1) * 64 + j * 16 + lane] = q[j];
    }
  }
  __syncthreads();
  if (lay == 0 && t < 128) {
    int col = blockIdx.y * 128 + t;
    if (col < PCOLS) {
      ps[((size_t)blockIdx.x * MM_ + 0) * PCOLS + col] = rs[0][t] + rs[1][t];
      pq[((size_t)blockIdx.x * MM_ + 0) * PCOLS + col] = rq[0][t] + rq[1][t];
    }
  }
}

// ---- module GEMM: mo[b][m][:] = A_m[b][:] @ W'_m + b'_m; fused mo stats
__global__ __launch_bounds__(256, 4) void k_gemm_mod(
    const bf16_t* __restrict__ Abase, int lda, int mstride,
    const bf16_t* __restrict__ WtM, const float* __restrict__ bM,
    bf16_t* __restrict__ mo,
    float* __restrict__ ps, float* __restrict__ pq,
    const int* __restrict__ layC)
{
  __shared__ bf16_t sAB[4 * 4096];
  __shared__ float rs[2][128], rq[2][128];
  const int lay = layC[0];
  const int m = blockIdx.z;
  const int t = threadIdx.x;
  const int w = t >> 6, lane = t & 63;
  const int rr = lane & 15, qq = lane >> 4;
  const int wr = (w >> 1) * 64, wc = (w & 1) * 64;
  const int rowT = blockIdx.x * 128, colT = blockIdx.y * 128;
  f32x4 acc[4][4]; acc_zero(acc);
  gemm_staged<13>(Abase + (size_t)m * mstride + (size_t)rowT * lda, lda,
                  WtM + (size_t)m * DHA_ * DHP_ + (size_t)colT * DHP_, DHP_,
                  sAB, sAB + 8192, wr, wc, rr, qq, t, acc);
  const int row0 = rowT + wr, col0 = colT + wc;
  float bjv[4];
  bool cok[4];
#pragma unroll
  for (int j = 0; j < 4; ++j) {
    int c = col0 + j * 16 + rr;
    bjv[j] = bM[m * DHA_ + c];
    cok[j] = (c < DHP_);
  }
  float s[4] = {0.f, 0.f, 0.f, 0.f}, q[4] = {0.f, 0.f, 0.f, 0.f};
  if (lay == 0) {
#pragma unroll
    for (int j = 0; j < 4; ++j) {
      if (!cok[j]) continue;
#pragma unroll
      for (int i = 0; i < 4; ++i)
#pragma unroll
        for (int e = 0; e < 4; ++e) {
          float v = acc[i][j][e] + bjv[j];
          s[j] += v; q[j] += v * v;
        }
    }
    bf16_t* eld = sAB + w * 2304;     // 32 rows x stride 72
#pragma unroll
    for (int p = 0; p < 2; ++p) {
#pragma unroll
      for (int ii = 0; ii < 2; ++ii) {
        int i = p * 2 + ii;
#pragma unroll
        for (int j = 0; j < 4; ++j)
#pragma unroll
          for (int e = 0; e < 4; ++e)
            eld[(ii * 16 + qq * 4 + e) * 72 + j * 16 + rr] = (bf16_t)(acc[i][j][e] + bjv[j]);
      }
#pragma unroll
      for (int rb = 0; rb < 4; ++rb) {
        int rl = rb * 8 + (lane >> 3);
        int c8 = (lane & 7) * 8;
        bf16x8 vv = *reinterpret_cast<const bf16x8*>(eld + rl * 72 + c8);
        int row = row0 + p * 32 + rl;
        int col = colT + wc + c8;
        if (col < DHP_)
          *reinterpret_cast<bf16x8*>(mo + ((size_t)row * MM_ + m) * DHP_ + col) = vv;
      }
    }
  } else {
#pragma unroll
    for (int j = 0; j < 4; ++j) {
#pragma unroll
      for (int i = 0; i < 4; ++i) {
#pragma unroll
        for (int e = 0; e < 4; ++e) {
          int row = row0 + i * 16 + rr;
          int col = col0 + j * 16 + qq * 4 + e;
          if (col >= DHP_) continue;
          float v = acc[i][j][e] + bM[m * DHA_ + col];
          mo[((size_t)row * MM_ + m) * DHP_ + col] = (bf16_t)v;
        }
      }
    }
  }
#pragma unroll
  for (int j = 0; j < 4; ++j) {
    s[j] += __shfl_xor(s[j], 16); s[j] += __shfl_xor(s[j], 32);
    q[j] += __shfl_xor(q[j], 16); q[j] += __shfl_xor(q[j], 32);
  }
  if (lane < 16) {
#pragma unroll
    for (int j = 0; j < 4; ++j) {
      rs[w >> 1][(w & 1) * 64 + j * 16 + lane] = s[j];
      rq[w >> 1][(w & 1) * 64 + j * 16 + lane] = q[j];
    }
  }
  __syncthreads();
  if (lay == 0 && t < 128) {
    int col = blockIdx.y * 128 + t;
    if (col < PCOLS) {
      ps[((size_t)blockIdx.x * MM_ + m) * PCOLS + col] = rs[0][t] + rs[1][t];
      pq[((size_t)blockIdx.x * MM_ + m) * PCOLS + col] = rq[0][t] + rq[1][t];
    }
  }
}

// ---------------- partials -> BN scale/shift (parallel, unrolled) ------------
template<int NCHT>
__global__ __launch_bounds__(512) void k_bnprep2(
    const float* __restrict__ ps, const float* __restrict__ pq, int per_m,
    const bf16_t* __restrict__ g, const bf16_t* __restrict__ b,
    float* __restrict__ s_o, float* __restrict__ t_o)
{
  __shared__ float lS[8][64], lQ[8][64];
  const int m = blockIdx.x, cg = blockIdx.y;
  const int sub = threadIdx.x >> 6, lane = threadIdx.x & 63;
  const int k = cg * 64 + lane;
  const int mm = per_m ? m : 0;
  float S = 0.f, Q = 0.f;
#pragma unroll 8
  for (int ch = sub; ch < NCHT; ch += 8) {
    size_t idx = ((size_t)ch * MM_ + mm) * PCOLS + k;
    S += ps[idx];
    Q += pq[idx];
  }
  lS[sub][lane] = S; lQ[sub][lane] = Q;
  __syncthreads();
  if (sub == 0 && k < DHP_) {
    float St = 0.f, Qt = 0.f;
#pragma unroll
    for (int i = 0; i < 8; ++i) { St += lS[i][lane]; Qt += lQ[i][lane]; }
    float s = 0.f, t = 0.f;
    if (k < DH_) {
      float mean = St * (1.f / BN_);
      float var  = fmaxf(Qt * (1.f / BN_) - mean * mean, 0.f);
      float rstd = rsqrtf(var + EPS_);
      s = (float)g[m * DH_ + k] * rstd;
      t = (float)b[m * DH_ + k] - mean * s;
    }
    s_o[m * DHP_ + k] = s;
    t_o[m * DHP_ + k] = t;
  }
}

// ---------------- routing mix + fused BN1 stats of mi ------------------------
__global__ __launch_bounds__(256) void k_mix(
    const bf16_t* __restrict__ mo, const float* __restrict__ s2v, const float* __restrict__ t2v,
    const float* __restrict__ wbuf, int woff, bf16_t* __restrict__ mi,
    float* __restrict__ ps, float* __restrict__ pq)
{
  __shared__ float sB[4 * 416], qB[4 * 416];
  const int ch = blockIdx.x;
  const int wave = threadIdx.x >> 6, lane = threadIdx.x & 63;
  const int d0 = lane * 8;
  float sx[4][8], tx[4][8];
  float sAcc[4][8], qAcc[4][8];
#pragma unroll
  for (int j = 0; j < 4; ++j)
#pragma unroll
    for (int e = 0; e < 8; ++e) { sAcc[j][e] = 0.f; qAcc[j][e] = 0.f; }
  if (lane < 52) {
#pragma unroll
    for (int k = 0; k < 4; ++k)
#pragma unroll
      for (int e = 0; e < 8; ++e) {
        sx[k][e] = s2v[k * DHP_ + d0 + e];
        tx[k][e] = t2v[k * DHP_ + d0 + e];
      }
  }
#pragma unroll 1
  for (int i = 0; i < 16; ++i) {
    int b = ch * 64 + wave + i * 4;
    float wv = (lane < 16) ? wbuf[(size_t)b * 52 + woff + lane] : 0.f;
    if (lane < 52) {
      float x[4][8];
#pragma unroll
      for (int k = 0; k < 4; ++k) {
        bf16x8 v = *reinterpret_cast<const bf16x8*>(mo + ((size_t)b * MM_ + k) * DHP_ + d0);
#pragma unroll
        for (int e = 0; e < 8; ++e)
          x[k][e] = (float)v[e] * sx[k][e] + tx[k][e];
      }
#pragma unroll
      for (int j = 0; j < 4; ++j) {
        float w0 = __shfl(wv, j * 4 + 0), w1 = __shfl(wv, j * 4 + 1);
        float w2 = __shfl(wv, j * 4 + 2), w3 = __shfl(wv, j * 4 + 3);
        bf16x8 ov;
#pragma unroll
        for (int e = 0; e < 8; ++e) {
          float a = fmaxf(x[0][e] * w0 + x[1][e] * w1 + x[2][e] * w2 + x[3][e] * w3, 0.f);
          ov[e] = (bf16_t)a;
          float r = (float)ov[e];          // stats of the stored (rounded) value
          sAcc[j][e] += r; qAcc[j][e] += r * r;
        }
        *reinterpret_cast<bf16x8*>(mi + ((size_t)b * MM_ + j) * DHP_ + d0) = ov;
      }
    }
  }
  // deterministic cross-wave reduce
#pragma unroll 1
  for (int w = 0; w < 4; ++w) {
    if (wave == w && lane < 52) {
#pragma unroll
      for (int j = 0; j < 4; ++j)
#pragma unroll
        for (int e = 0; e < 8; ++e) {
          int idx = j * 416 + d0 + e;
          if (w == 0) { sB[idx] = sAcc[j][e]; qB[idx] = qAcc[j][e]; }
          else        { sB[idx] += sAcc[j][e]; qB[idx] += qAcc[j][e]; }
        }
    }
    __syncthreads();
  }
  for (int idx = threadIdx.x; idx < 4 * 416; idx += 256) {
    int j = idx / 416, col = idx - j * 416;
    ps[((size_t)ch * MM_ + j) * PCOLS + col] = sB[idx];
    pq[((size_t)ch * MM_ + j) * PCOLS + col] = qB[idx];
  }
}

// ------------- gating cascade v5 (measured-best): 4 indep waves/block, 2 samp/wave
__global__ __launch_bounds__(256) void k_gate(
    const bf16_t* __restrict__ emb,
    const bf16_t* __restrict__ gw0t, const bf16_t* __restrict__ gw0_b,
    const bf16_t* __restrict__ c1_w,  const bf16_t* __restrict__ c1_b,
    const bf16_t* __restrict__ gw1t, const bf16_t* __restrict__ gw1_b,
    const bf16_t* __restrict__ c2_w,  const bf16_t* __restrict__ c2_b,
    const bf16_t* __restrict__ gw2t, const bf16_t* __restrict__ gw2_b,
    const bf16_t* __restrict__ cL_w,  const bf16_t* __restrict__ cL_b,
    const bf16_t* __restrict__ gwLt, const bf16_t* __restrict__ gwL_b,
    float* __restrict__ wbuf)
{
  __shared__ float VBA[4][272], VBB[4][272];
  __shared__ float FLA[4][64], FLB[4][64];
  const int wave = threadIdx.x >> 6, lane = threadIdx.x & 63;
  float* vbA = VBA[wave];
  float* vbB = VBB[wave];
  float* flA = FLA[wave];
  float* flB = FLB[wave];
  const int bA = blockIdx.x * 8 + wave * 2, bB = bA + 1;
  const int wrIdx = lane * 4 + (lane >> 4) * 4;

  float eA[4], eB[4];
  {
    bf16x4 evA = *reinterpret_cast<const bf16x4*>(emb + (size_t)bA * GH_ + lane * 4);
    bf16x4 evB = *reinterpret_cast<const bf16x4*>(emb + (size_t)bB * GH_ + lane * 4);
    f32x4 rA, rB;
#pragma unroll
    for (int e = 0; e < 4; ++e) {
      eA[e] = (float)evA[e]; rA[e] = fmaxf(eA[e], 0.f);
      eB[e] = (float)evB[e]; rB[e] = fmaxf(eB[e], 0.f);
    }
    *reinterpret_cast<f32x4*>(vbA + wrIdx) = rA;
    *reinterpret_cast<f32x4*>(vbB + wrIdx) = rB;
  }
  __builtin_amdgcn_wave_barrier();

  const int hh = lane >> 4, jj = lane & 15;

  auto softmax4 = [&](float a) -> float {
    float m1 = fmaxf(a, __shfl_xor(a, 1));
    float mx = fmaxf(m1, __shfl_xor(m1, 2));
    float ex = __expf(a - mx);
    float sx = ex + __shfl_xor(ex, 1);
    float sm = sx + __shfl_xor(sx, 2);
    return ex / sm;
  };

  auto gw_phase = [&](const bf16_t* Wt, const bf16_t* Bb, int foff) {
    float a0A = 0.f, a1A = 0.f, a0B = 0.f, a1B = 0.f;
#pragma unroll
    for (int cc = 0; cc < 8; ++cc) {
      int c8 = (cc + hh * 2) & 7;
      int k  = hh * 64 + c8 * 8;
      int idx = k + hh * 4;
      f32x4 vA0 = *reinterpret_cast<const f32x4*>(vbA + idx);
      f32x4 vA1 = *reinterpret_cast<const f32x4*>(vbA + idx + 4);
      f32x4 vB0 = *reinterpret_cast<const f32x4*>(vbB + idx);
      f32x4 vB1 = *reinterpret_cast<const f32x4*>(vbB + idx + 4);
      bf16x8 wv = *reinterpret_cast<const bf16x8*>(Wt + jj * 256 + k);
      float w0 = (float)wv[0], w1 = (float)wv[1], w2 = (float)wv[2], w3 = (float)wv[3];
      float w4 = (float)wv[4], w5 = (float)wv[5], w6 = (float)wv[6], w7 = (float)wv[7];
      a0A = fmaf(vA0[0], w0, a0A); a0A = fmaf(vA0[1], w1, a0A);
      a0A = fmaf(vA0[2], w2, a0A); a0A = fmaf(vA0[3], w3, a0A);
      a1A = fmaf(vA1[0], w4, a1A); a1A = fmaf(vA1[1], w5, a1A);
      a1A = fmaf(vA1[2], w6, a1A); a1A = fmaf(vA1[3], w7, a1A);
      a0B = fmaf(vB0[0], w0, a0B); a0B = fmaf(vB0[1], w1, a0B);
      a0B = fmaf(vB0[2], w2, a0B); a0B = fmaf(vB0[3], w3, a0B);
      a1B = fmaf(vB1[0], w4, a1B); a1B = fmaf(vB1[1], w5, a1B);
      a1B = fmaf(vB1[2], w6, a1B); a1B = fmaf(vB1[3], w7, a1B);
    }
    float aA = a0A + a1A, aB = a0B + a1B;
    aA += __shfl_xor(aA, 16); aA += __shfl_xor(aA, 32);
    aB += __shfl_xor(aB, 16); aB += __shfl_xor(aB, 32);
    float bb = (float)Bb[jj];
    aA += bb; aB += bb;
    float wA = softmax4(aA), wB = softmax4(aB);
    if (lane < 16) {
      flA[foff + jj] = wA; wbuf[(size_t)bA * 52 + foff + jj] = wA;
      flB[foff + jj] = wB; wbuf[(size_t)bB * 52 + foff + jj] = wB;
    }
    __builtin_amdgcn_wave_barrier();
  };

  auto cond_phase = [&](const bf16_t* W, const bf16_t* Bb, int tcount) {
    float a4A[4], a4B[4];
    bf16x4 bb = *reinterpret_cast<const bf16x4*>(Bb + lane * 4);
#pragma unroll
    for (int e = 0; e < 4; ++e) { a4A[e] = (float)bb[e]; a4B[e] = a4A[e]; }
    for (int t = 0; t < tcount; ++t) {
      float fA = flA[t], fB = flB[t];
      bf16x4 wv = *reinterpret_cast<const bf16x4*>(W + t * 256 + lane * 4);
#pragma unroll
      for (int e = 0; e < 4; ++e) {
        float w = (float)wv[e];
        a4A[e] = fmaf(fA, w, a4A[e]);
        a4B[e] = fmaf(fB, w, a4B[e]);
      }
    }
    f32x4 rA, rB;
#pragma unroll
    for (int e = 0; e < 4; ++e) {
      rA[e] = fmaxf(a4A[e] * eA[e], 0.f);
      rB[e] = fmaxf(a4B[e] * eB[e], 0.f);
    }
    *reinterpret_cast<f32x4*>(vbA + wrIdx) = rA;
    *reinterpret_cast<f32x4*>(vbB + wrIdx) = rB;
    __builtin_amdgcn_wave_barrier();
  };

  gw_phase(gw0t, gw0_b, 0);
  cond_phase(c1_w, c1_b, 16);
  gw_phase(gw1t, gw1_b, 16);
  cond_phase(c2_w, c2_b, 32);
  gw_phase(gw2t, gw2_b, 32);
  cond_phase(cL_w, cL_b, 48);
  {
    const int j4 = lane & 3, h16 = lane >> 2;
    const int base = h16 * 16 + (h16 >> 2) * 4;
    bf16x8 w0 = *reinterpret_cast<const bf16x8*>(gwLt + j4 * 256 + h16 * 16);
    bf16x8 w1 = *reinterpret_cast<const bf16x8*>(gwLt + j4 * 256 + h16 * 16 + 8);
    float aA = 0.f, aB = 0.f;
#pragma unroll
    for (int c = 0; c < 2; ++c) {
      f32x4 vA0 = *reinterpret_cast<const f32x4*>(vbA + base + c * 8);
      f32x4 vA1 = *reinterpret_cast<const f32x4*>(vbA + base + c * 8 + 4);
      f32x4 vB0 = *reinterpret_cast<const f32x4*>(vbB + base + c * 8);
      f32x4 vB1 = *reinterpret_cast<const f32x4*>(vbB + base + c * 8 + 4);
      const bf16x8& w = c ? w1 : w0;
#pragma unroll
      for (int e = 0; e < 4; ++e) {
        aA = fmaf(vA0[e], (float)w[e], aA);
        aA = fmaf(vA1[e], (float)w[e + 4], aA);
        aB = fmaf(vB0[e], (float)w[e], aB);
        aB = fmaf(vB1[e], (float)w[e + 4], aB);
      }
    }
    aA += __shfl_xor(aA, 4); aA += __shfl_xor(aA, 8);
    aA += __shfl_xor(aA, 16); aA += __shfl_xor(aA, 32);
    aB += __shfl_xor(aB, 4); aB += __shfl_xor(aB, 8);
    aB += __shfl_xor(aB, 16); aB += __shfl_xor(aB, 32);
    float bb = (float)gwL_b[j4];
    aA += bb; aB += bb;
    float wA = softmax4(aA), wB = softmax4(aB);
    if (lane < 4) {
      wbuf[(size_t)bA * 52 + 48 + j4] = wA;
      wbuf[(size_t)bB * 52 + 48 + j4] = wB;
    }
  }
}

// ------------- final: BN2-affine, last_weight mix, relu, @last_w + last_b ----
__global__ __launch_bounds__(256) void k_final(
    const bf16_t* __restrict__ mo, const float* __restrict__ s2v, const float* __restrict__ t2v,
    const float* __restrict__ wbuf, const bf16_t* __restrict__ last_w,
    const bf16_t* __restrict__ last_b, void* __restrict__ outv,
    const int* __restrict__ flag)
{
  const int f32out = flag[0];
  const int wave = threadIdx.x >> 6, lane = threadIdx.x & 63;
  const int d0 = lane * 8;
  float sx[4][8], tx[4][8];
  if (lane < 52) {
#pragma unroll
    for (int k = 0; k < 4; ++k)
#pragma unroll
      for (int e = 0; e < 8; ++e) {
        sx[k][e] = s2v[k * DHP_ + d0 + e];
        tx[k][e] = t2v[k * DHP_ + d0 + e];
      }
  }
  for (int b = blockIdx.x * 4 + wave; b < BN_; b += gridDim.x * 4) {
    const float* lwp = wbuf + (size_t)b * 52 + 48;
    float lm0 = lwp[0], lm1 = lwp[1], lm2 = lwp[2], lm3 = lwp[3];
    float slm = lm0 + lm1 + lm2 + lm3;
    const float* w0p = wbuf + (size_t)b * 52;
    float sw0 = w0p[0] + w0p[1] + w0p[2] + w0p[3];
    float p[8];
#pragma unroll
    for (int j = 0; j < 8; ++j) p[j] = 0.f;
    if (lane < 52) {
      float x[4][8];
#pragma unroll
      for (int k = 0; k < 4; ++k) {
        bf16x8 v = *reinterpret_cast<const bf16x8*>(mo + ((size_t)b * MM_ + k) * DHP_ + d0);
#pragma unroll
        for (int e = 0; e < 8; ++e)
          x[k][e] = (float)v[e] * sx[k][e] + tx[k][e];
      }
#pragma unroll
      for (int e = 0; e < 8; ++e) {
        float v = fmaxf(x[0][e] * lm0 + x[1][e] * lm1 + x[2][e] * lm2 + x[3][e] * lm3, 0.f);
        bf16x8 wv = *reinterpret_cast<const bf16x8*>(last_w + (size_t)(d0 + e) * 8);
#pragma unroll
        for (int j = 0; j < 8; ++j) p[j] = fmaf(v, (float)wv[j], p[j]);
      }
    }
#pragma unroll
    for (int j = 0; j < 8; ++j) {
      p[j] += __shfl_xor(p[j], 1);
      p[j] += __shfl_xor(p[j], 2);
      p[j] += __shfl_xor(p[j], 4);
      p[j] += __shfl_xor(p[j], 8);
      p[j] += __shfl_xor(p[j], 16);
      p[j] += __shfl_xor(p[j], 32);
    }
    float sel = p[0];
#pragma unroll
    for (int j = 1; j < 8; ++j) if (lane == j) sel = p[j];
    if (lane < 8) {
      float res = sel + (float)last_b[lane];
      if (!(fabsf(res) < 1e4f)) res = 400.f;
      if (!(slm > 0.97f && slm < 1.03f)) res = 1000.f;
      if (!(sw0 > 0.97f && sw0 < 1.03f)) res = 2000.f;
      if (f32out) ((float*)outv)[(size_t)b * 8 + lane] = res;
      else ((bf16_t*)outv)[(size_t)b * 8 + lane] = (bf16_t)res;
    }
  }
}

// ======================================================================
extern "C" void kernel_launch(void* const* d_in, const int* in_sizes, int n_in,
                              void* d_out, int out_size, void* d_ws, size_t ws_size,
                              hipStream_t stream)
{
  (void)in_sizes; (void)n_in;
  const void* x_raw   = d_in[0];
  const void* emb_raw = d_in[1];
  const void* base_w1 = d_in[2];
  const void* base_w2 = d_in[4];
  const void* em_w    = d_in[6];
  const void* gfc_w1  = d_in[8];
  const void* gfc_w2  = d_in[10];
  const void* modW_raw= d_in[28];

  char* base = (char*)d_ws;
  size_t off = 0;
  auto alloc = [&](size_t bytes) -> char* {
    off = (off + 255) & ~(size_t)255;
    char* r = base + off; off += bytes; return r;
  };
  int*    dflag = (int*)   alloc(16);
  int*    layC  = (int*)   alloc(16);
  bf16_t* Wt1  = (bf16_t*)alloc((size_t)512 * 128 * 2);
  bf16_t* Wem  = (bf16_t*)alloc((size_t)512 * 64 * 2);
  bf16_t* Wt2  = (bf16_t*)alloc((size_t)512 * DHP_ * 2);
  bf16_t* Wg1  = (bf16_t*)alloc((size_t)256 * DHP_ * 2);
  bf16_t* Wg2  = (bf16_t*)alloc((size_t)256 * 256 * 2);
  bf16_t* WtM  = (bf16_t*)alloc((size_t)MM_ * DHA_ * DHP_ * 2);
  float*  bM   = (float*) alloc((size_t)MM_ * DHA_ * 4);
  bf16_t* xc   = (bf16_t*)alloc((size_t)BN_ * DIN_ * 2);
  bf16_t* embc = (bf16_t*)alloc((size_t)BN_ * DEM_ * 2);
  bf16_t* out1 = (bf16_t*)alloc((size_t)BN_ * DHP_ * 2);
  bf16_t* emb0 = (bf16_t*)alloc((size_t)BN_ * DHP_ * 2);
  bf16_t* outA = (bf16_t*)alloc((size_t)BN_ * DHP_ * 2);
  bf16_t* emb1 = (bf16_t*)alloc((size_t)BN_ * DHP_ * 2);
  bf16_t* embF = (bf16_t*)alloc((size_t)BN_ * GH_ * 2);
  float*  wbuf = (float*) alloc((size_t)BN_ * 52 * 4);
  bf16_t* mo   = (bf16_t*)alloc((size_t)BN_ * MM_ * DHP_ * 2);
  bf16_t* mi   = (bf16_t*)alloc((size_t)BN_ * MM_ * DHP_ * 2);
  float* psO = (float*)alloc((size_t)NCH * MM_ * PCOLS * 4);
  float* pqO = (float*)alloc((size_t)NCH * MM_ * PCOLS * 4);
  float* psA = (float*)alloc((size_t)NCHMI * MM_ * PCOLS * 4);
  float* pqA = (float*)alloc((size_t)NCHMI * MM_ * PCOLS * 4);
  float* psB = (float*)alloc((size_t)NCH * MM_ * PCOLS * 4);
  float* pqB = (float*)alloc((size_t)NCH * MM_ * PCOLS * 4);
  float* s2 = (float*)alloc((size_t)MM_ * DHP_ * 4);
  float* t2 = (float*)alloc((size_t)MM_ * DHP_ * 4);
  bf16_t* gw0t = (bf16_t*)alloc((size_t)16 * 256 * 2);
  bf16_t* gw1t = (bf16_t*)alloc((size_t)16 * 256 * 2);
  bf16_t* gw2t = (bf16_t*)alloc((size_t)16 * 256 * 2);
  bf16_t* gwLt = (bf16_t*)alloc((size_t)4 * 256 * 2);
  const int sn[NS_] = {400, 400, 400, 256, 256,
                       4096, 16, 4096, 256, 4096, 16, 8192, 256, 4096, 16,
                       12288, 256, 1024, 4,
                       6400, 6400, 6400, 6400, 6400, 3200, 8};
  const int si[NS_] = {3, 5, 7, 9, 11,
                       12, 13, 14, 15, 16, 17, 18, 19, 20, 21,
                       22, 23, 24, 25,
                       26, 27, 29, 30, 31, 32, 33};
  bf16_t* sc[NS_];
  for (int i = 0; i < NS_; ++i) sc[i] = (bf16_t*)alloc((size_t)sn[i] * 2);
  bf16_t *b1c = sc[0], *b2c = sc[1], *embbc = sc[2], *g1bc = sc[3], *g2bc = sc[4];
  bf16_t *gw0b = sc[6], *c1w = sc[7], *c1b = sc[8],
         *gw1b = sc[10], *c2w = sc[11], *c2b = sc[12], *gw2b = sc[14],
         *cLw = sc[15], *cLb = sc[16], *gwLb = sc[18];
  bf16_t *bn1g = sc[19], *bn1b = sc[20], *modbc = sc[21], *bn2g = sc[22], *bn2b = sc[23];
  bf16_t *lastw = sc[24], *lastb = sc[25];

  if (off > ws_size) {
    hipMemsetAsync(d_out, 0, (size_t)out_size * 2, stream);
    return;
  }

  dim3 blk(256);
  k_detect_probe<<<1, blk, 0, stream>>>((const unsigned*)x_raw, dflag, layC);

  // all transposes + ALL conversions in ONE dispatch
  SmallTab tab;
  for (int i = 0; i < NS_; ++i) { tab.src[i] = d_in[si[i]]; tab.dst[i] = sc[i]; tab.n[i] = sn[i]; }
  Cvt2 cv;
  cv.src1 = x_raw;   cv.dst1 = xc;   cv.n1 = BN_ * DIN_;
  cv.src2 = emb_raw; cv.dst2 = embc; cv.n2 = BN_ * DEM_;
  TransTab tt;
  tt.src[0] = base_w1;  tt.dst[0] = Wt1;  tt.K[0] = DIN_; tt.N[0] = DH_; tt.KP[0] = 128;  tt.NPa[0] = 512; tt.usef[0] = 1;
  tt.src[1] = em_w;     tt.dst[1] = Wem;  tt.K[1] = DEM_; tt.N[1] = DH_; tt.KP[1] = 64;   tt.NPa[1] = 512; tt.usef[1] = 1;
  tt.src[2] = base_w2;  tt.dst[2] = Wt2;  tt.K[2] = DH_;  tt.N[2] = DH_; tt.KP[2] = DHP_; tt.NPa[2] = 512; tt.usef[2] = 1;
  tt.src[3] = gfc_w1;   tt.dst[3] = Wg1;  tt.K[3] = DH_;  tt.N[3] = GH_; tt.KP[3] = DHP_; tt.NPa[3] = 256; tt.usef[3] = 1;
  tt.src[4] = gfc_w2;   tt.dst[4] = Wg2;  tt.K[4] = GH_;  tt.N[4] = GH_; tt.KP[4] = 256;  tt.NPa[4] = 256; tt.usef[4] = 1;
  tt.src[5] = d_in[12]; tt.dst[5] = gw0t; tt.K[5] = 256;  tt.N[5] = 16;  tt.KP[5] = 256;  tt.NPa[5] = 16;  tt.usef[5] = 1;
  tt.src[6] = d_in[16]; tt.dst[6] = gw1t; tt.K[6] = 256;  tt.N[6] = 16;  tt.KP[6] = 256;  tt.NPa[6] = 16;  tt.usef[6] = 1;
  tt.src[7] = d_in[20]; tt.dst[7] = gw2t; tt.K[7] = 256;  tt.N[7] = 16;  tt.KP[7] = 256;  tt.NPa[7] = 16;  tt.usef[7] = 1;
  tt.src[8] = d_in[24]; tt.dst[8] = gwLt; tt.K[8] = 256;  tt.N[8] = 4;   tt.KP[8] = 256;  tt.NPa[8] = 4;   tt.usef[8] = 1;
  k_transAll<<<dim3(7, 8, NT_ + 1 + CVZ), blk, 0, stream>>>(tt, tab, cv, dflag);

  // front MLPs: the two independent input GEMMs fused into one dispatch
  k_gemm_front_pair<<<dim3(128, 4, 2), blk, 0, stream>>>(
      xc, embc, Wt1, Wem, b1c, embbc, out1, emb0, layC);
  k_gemm_base2<<<dim3(128, 4), blk, 0, stream>>>(out1, Wt2, b2c, emb0, outA, emb1, psO, pqO, layC);
  bf16_t* emb2 = emb0;  // emb0 dead after base2 -> reuse
  k_gemm_bias<13, true , false><<<dim3(128, 2), blk, 0, stream>>>(emb1, DHP_, Wg1, DHP_, g1bc, GH_, emb2, GH_, GH_, layC);
  k_gemm_bias<8,  false, false><<<dim3(128, 2), blk, 0, stream>>>(emb2, GH_, Wg2, GH_, g2bc, GH_, embF, GH_, GH_, layC);

  // gating cascade (4 indep waves/block, 2 samples/wave — measured best)
  k_gate<<<dim3(BN_ / 8), blk, 0, stream>>>(embF,
      gw0t, gw0b, c1w, c1b, gw1t, gw1b, c2w, c2b, gw2t, gw2b,
      cLw, cLb, gwLt, gwLb, wbuf);

  // layer 0 (BN1 stats of outA inlined in prepW from psO)
  k_prepW<<<dim3(7, 9, 4), blk, 0, stream>>>(modW_raw, 0, modbc,
                                             psO, pqO, NCH, 0, bn1g, bn1b,
                                             WtM, bM, dflag);
  k_gemm_mod<<<dim3(128, 4, 4), blk, 0, stream>>>(outA, DHP_, 0, WtM, bM, mo, psB, pqB, layC);

  // layers 1..3
  for (int L = 1; L < 4; ++L) {
    k_bnprep2<NCH><<<dim3(4, 7), dim3(512), 0, stream>>>(psB, pqB, 1,
        bn2g + (size_t)(L - 1) * MM_ * DH_, bn2b + (size_t)(L - 1) * MM_ * DH_, s2, t2);
    k_mix<<<dim3(NCHMI), blk, 0, stream>>>(mo, s2, t2, wbuf, (L - 1) * 16, mi, psA, pqA);
    k_prepW<<<dim3(7, 9, 4), blk, 0, stream>>>(modW_raw, (size_t)L * MM_ * DH_ * DH_,
                                               modbc + (size_t)L * MM_ * DH_,
                                               psA, pqA, NCHMI, 1,
                                               bn1g + (size_t)L * MM_ * DH_, bn1b + (size_t)L * MM_ * DH_,
                                               WtM, bM, dflag);
    k_gemm_mod<<<dim3(128, 4, 4), blk, 0, stream>>>(mi, MM_ * DHP_, DHP_, WtM, bM, mo, psB, pqB, layC);
  }

  // final
  k_bnprep2<NCH><<<dim3(4, 7), dim3(512), 0, stream>>>(psB, pqB, 1,
      bn2g + (size_t)3 * MM_ * DH_, bn2b + (size_t)3 * MM_ * DH_, s2, t2);
  k_final<<<dim3(1024), blk, 0, stream>>>(mo, s2, t2, wbuf, lastw, lastb, d_out, dflag);
}

// Round 21
// 511.152 us; speedup vs baseline: 1.3782x; 1.3782x over previous
//
#include <hip/hip_runtime.h>
#include <hip/hip_bf16.h>

typedef __bf16 bf16_t;
typedef __bf16 bf16x8 __attribute__((ext_vector_type(8)));
typedef __bf16 bf16x4 __attribute__((ext_vector_type(4)));
typedef float  f32x4  __attribute__((ext_vector_type(4)));

#define BN_   16384
#define DIN_  128
#define DEM_  64
#define DH_   400
#define DHP_  416   // K padded to 32-multiple
#define DHA_  512   // N padded to 128-tile coverage
#define GH_   256
#define MM_   4
#define EPS_  1e-5f
#define PCOLS 448   // partial-stats column stride
#define NCH   128   // partial-stats chunks (GEMM-fused layout)
#define NCHMI 256   // partial-stats chunks (k_mix-fused layout)

// -------- fused dtype detector + MFMA C/D layout probe (one dispatch) --------
__global__ __launch_bounds__(256) void k_detect_probe(const unsigned* __restrict__ w,
                                                      int* __restrict__ flag,
                                                      int* __restrict__ layC)
{
  __shared__ int cnt[256];
  int c = 0;
  for (int i = 0; i < 16; ++i) {
    unsigned v = w[threadIdx.x * 16 + i];
    float lo = __uint_as_float((v & 0xffffu) << 16);
    if (!(fabsf(lo) < 1e4f)) ++c;
  }
  cnt[threadIdx.x] = c;
  __syncthreads();
  if (threadIdx.x == 0) {
    int t = 0;
    for (int i = 0; i < 256; ++i) t += cnt[i];
    flag[0] = (t > 64) ? 1 : 0;     // 1 = inputs are float32
  }
  if (threadIdx.x < 64) {
    int l = threadIdx.x;
    bf16x8 av, bv;
#pragma unroll
    for (int e = 0; e < 8; ++e) { av[e] = (bf16_t)0.f; bv[e] = (bf16_t)0.f; }
    if ((l >> 4) == 0) av[0] = (bf16_t)(float)(l & 15);
    if (l == 0)        bv[0] = (bf16_t)1.f;
    f32x4 acc = {0.f, 0.f, 0.f, 0.f};
    acc = __builtin_amdgcn_mfma_f32_16x16x32_bf16(av, bv, acc, 0, 0, 0);
    if (l == 1) layC[0] = (acc[0] > 0.5f) ? 1 : 0;
  }
}

#define NS_ 26
struct SmallTab {
  const void* src[NS_];
  bf16_t*     dst[NS_];
  int         n[NS_];
};

struct Cvt2 {
  const void* src1; bf16_t* dst1; int n1;
  const void* src2; bf16_t* dst2; int n2;
};

// -------- merged front/gate transposes + small converts + big converts -------
// z < NT_  : transpose tensor z (reads RAW d_in with dtype flag)
// z == NT_ : small-tensor conversions (flat block id over 7x8 grid)
// z >  NT_ : x/emb conversion slices (8 slices x 56 blocks, grid-stride)
#define NT_ 9
#define CVZ 8
struct TransTab {
  const void* src[NT_];
  bf16_t*     dst[NT_];
  int K[NT_], N[NT_], KP[NT_], NPa[NT_], usef[NT_];
};

__global__ __launch_bounds__(256) void k_transAll(TransTab tt, SmallTab st, Cvt2 cv,
                                                  const int* __restrict__ flag)
{
  __shared__ float T[64][65];
  const int z = blockIdx.z;
  if (z > NT_) {
    const int f = flag[0];
    const int slice = z - NT_ - 1;                        // 0..CVZ-1
    const int flat = slice * 56 + blockIdx.y * 7 + blockIdx.x;
    const int total = cv.n1 + cv.n2;
    for (int i = flat * 256 + threadIdx.x; i < total; i += 56 * CVZ * 256) {
      if (i < cv.n1)
        cv.dst1[i] = f ? (bf16_t)((const float*)cv.src1)[i] : ((const bf16_t*)cv.src1)[i];
      else {
        int j = i - cv.n1;
        cv.dst2[j] = f ? (bf16_t)((const float*)cv.src2)[j] : ((const bf16_t*)cv.src2)[j];
      }
    }
    return;
  }
  if (z == NT_) {
    const int f = flag[0];
    const int flat = blockIdx.y * 7 + blockIdx.x;
    if (flat >= NS_) return;
    const void* s = st.src[flat];
    bf16_t*     d = st.dst[flat];
    const int   n = st.n[flat];
    for (int i = threadIdx.x; i < n; i += 256)
      d[i] = f ? (bf16_t)((const float*)s)[i] : ((const bf16_t*)s)[i];
    return;
  }
  const int K = tt.K[z], N = tt.N[z], KP = tt.KP[z], NPa = tt.NPa[z];
  const int k0 = blockIdx.x * 64, n0 = blockIdx.y * 64;
  if (k0 >= KP || n0 >= NPa) return;
  const int f = tt.usef[z] ? flag[0] : 0;
  const float*  sf = (const float*) tt.src[z];
  const bf16_t* sb = (const bf16_t*)tt.src[z];
  bf16_t* dp = tt.dst[z];
  const int lr = threadIdx.x >> 6, ln = threadIdx.x & 63;
#pragma unroll
  for (int p = 0; p < 16; ++p) {
    int kl = p * 4 + lr;
    int k = k0 + kl, n = n0 + ln;
    float v = 0.f;
    if (k < K && n < N)
      v = f ? sf[(size_t)k * N + n] : (float)sb[(size_t)k * N + n];
    T[kl][ln] = v;
  }
  __syncthreads();
#pragma unroll
  for (int p = 0; p < 16; ++p) {
    int nl = p * 4 + lr;
    int n = n0 + nl, k = k0 + ln;
    if (n < NPa && k < KP) dp[(size_t)n * KP + k] = (bf16_t)T[ln][nl];
  }
}

// ---- merged per-layer module-weight prep: scaled transpose + bias fold ------
// grid (7, 9, 4): y<8 -> transpose tile; y==8 -> foldB (ncg = x)
// Consumes PRECOMPUTED s1/t1 from k_bnprep2 (round-20's inline recompute was a
// 4x79us latency-bound disaster: 252 blocks re-reading strided ps/pq at 4% occ)
__global__ __launch_bounds__(256) void k_prepW(
    const void* __restrict__ modW, size_t off, const bf16_t* __restrict__ modb,
    const float* __restrict__ s1v, const float* __restrict__ t1v,
    bf16_t* __restrict__ WtM, float* __restrict__ bM,
    const int* __restrict__ flag)
{
  __shared__ float T[64][65];
  const int f = flag[0];
  const int m = blockIdx.z;
  if (blockIdx.y == 8) {
    // b'_m[n] = mod_b[m][n] + sum_k shift[m][k]*W[m][k][n]
    float* ls = &T[0][0];
    const int ncg = blockIdx.x;
    const int t = threadIdx.x;
    const int n = ncg * 64 + (t & 63);
    const int ks = t >> 6;
    float a = 0.f;
    if (n < DH_) {
      for (int k = ks * 100; k < ks * 100 + 100; ++k) {
        size_t idx = off + ((size_t)m * DH_ + k) * DH_ + n;
        float wv = f ? ((const float*)modW)[idx] : (float)((const bf16_t*)modW)[idx];
        a += t1v[m * DHP_ + k] * wv;
      }
    }
    ls[t] = a;
    __syncthreads();
    if (t < 64) {
      int nn = ncg * 64 + t;
      float v = ls[t] + ls[t + 64] + ls[t + 128] + ls[t + 192];
      if (nn < DH_) v += (float)modb[m * DH_ + nn];
      else v = 0.f;
      bM[m * DHA_ + nn] = v;
    }
    if (ncg == 6 && t < 64) bM[m * DHA_ + 448 + t] = 0.f;
    return;
  }
  // scaled transpose: W'_m[n][k] = scale[m][k] * W[m][k][n]
  const float*  sf = (const float*) modW + off + (size_t)m * DH_ * DH_;
  const bf16_t* sb = (const bf16_t*)modW + off + (size_t)m * DH_ * DH_;
  bf16_t* dp = WtM + (size_t)m * DHA_ * DHP_;
  const int k0 = blockIdx.x * 64, n0 = blockIdx.y * 64;
  const int lr = threadIdx.x >> 6, ln = threadIdx.x & 63;
#pragma unroll
  for (int p = 0; p < 16; ++p) {
    int kl = p * 4 + lr;
    int k = k0 + kl, n = n0 + ln;
    float v = 0.f;
    if (k < DH_ && n < DH_)
      v = f ? sf[(size_t)k * DH_ + n] : (float)sb[(size_t)k * DH_ + n];
    if (k < DH_) v *= s1v[m * DHP_ + k];
    T[kl][ln] = v;
  }
  __syncthreads();
#pragma unroll
  for (int p = 0; p < 16; ++p) {
    int nl = p * 4 + lr;
    int n = n0 + nl, k = k0 + ln;
    if (n < DHA_ && k < DHP_) dp[(size_t)n * DHP_ + k] = (bf16_t)T[ln][nl];
  }
}

// ------------------------- staged GEMM core (m97 structure + T2 swizzle) -----
__device__ __forceinline__ void gload_lds16(const bf16_t* g, bf16_t* l) {
#if __has_builtin(__builtin_amdgcn_global_load_lds)
  __builtin_amdgcn_global_load_lds((const __attribute__((address_space(1))) void*)g,
                                   (__attribute__((address_space(3))) void*)l, 16, 0, 0);
#else
  *(bf16x8*)l = *(const bf16x8*)g;
#endif
}

__device__ __forceinline__ void stage128x32(const bf16_t* __restrict__ g, int ld,
                                            bf16_t* lds, int t) {
  const int c1 = t + 256;
  const int q0 = ((t  & 3) ^ ((t  >> 3) & 3)) * 8;
  const int q1 = ((c1 & 3) ^ ((c1 >> 3) & 3)) * 8;
  gload_lds16(g + (size_t)(t  >> 2) * ld + q0, lds + t  * 8);
  gload_lds16(g + (size_t)(c1 >> 2) * ld + q1, lds + c1 * 8);
}

__device__ __forceinline__ void acc_zero(f32x4 (&acc)[4][4]) {
  const f32x4 z = {0.f, 0.f, 0.f, 0.f};
#pragma unroll
  for (int i = 0; i < 4; ++i)
#pragma unroll
    for (int j = 0; j < 4; ++j) acc[i][j] = z;
}

// single-barrier double-buffer; trailing barrier frees staging LDS for epilogue
template<int KS>
__device__ __forceinline__ void gemm_staged(
    const bf16_t* __restrict__ ga, int lda,
    const bf16_t* __restrict__ gb, int ldb,
    bf16_t* ldsA, bf16_t* ldsB,
    int wr, int wc, int rr, int qq, int t,
    f32x4 (&acc)[4][4])
{
  const int qs = (qq ^ ((rr >> 1) & 3)) * 8;
  stage128x32(ga, lda, ldsA, t);
  stage128x32(gb, ldb, ldsB, t);
  int cur = 0;
#pragma unroll 1
  for (int ks = 0; ks < KS; ++ks) {
    __syncthreads();
    if (ks + 1 < KS) {
      stage128x32(ga + (ks + 1) * 32, lda, ldsA + (cur ^ 1) * 4096, t);
      stage128x32(gb + (ks + 1) * 32, ldb, ldsB + (cur ^ 1) * 4096, t);
    }
    const bf16_t* la = ldsA + cur * 4096;
    const bf16_t* lb = ldsB + cur * 4096;
    bf16x8 av[4], bv[4];
#pragma unroll
    for (int i = 0; i < 4; ++i)
      av[i] = *reinterpret_cast<const bf16x8*>(la + (wr + i * 16 + rr) * 32 + qs);
#pragma unroll
    for (int i = 0; i < 4; ++i)
      bv[i] = *reinterpret_cast<const bf16x8*>(lb + (wc + i * 16 + rr) * 32 + qs);
#pragma unroll
    for (int i = 0; i < 4; ++i)
#pragma unroll
      for (int j = 0; j < 4; ++j)
        acc[i][j] = __builtin_amdgcn_mfma_f32_16x16x32_bf16(av[i], bv[j], acc[i][j], 0, 0, 0);
    cur ^= 1;
  }
  __syncthreads();
}

// runtime-KS variant (for the merged front pair)
__device__ __forceinline__ void gemm_staged_rt(
    const bf16_t* __restrict__ ga, int lda,
    const bf16_t* __restrict__ gb, int ldb,
    bf16_t* ldsA, bf16_t* ldsB,
    int wr, int wc, int rr, int qq, int t, int KS,
    f32x4 (&acc)[4][4])
{
  const int qs = (qq ^ ((rr >> 1) & 3)) * 8;
  stage128x32(ga, lda, ldsA, t);
  stage128x32(gb, ldb, ldsB, t);
  int cur = 0;
#pragma unroll 1
  for (int ks = 0; ks < KS; ++ks) {
    __syncthreads();
    if (ks + 1 < KS) {
      stage128x32(ga + (ks + 1) * 32, lda, ldsA + (cur ^ 1) * 4096, t);
      stage128x32(gb + (ks + 1) * 32, ldb, ldsB + (cur ^ 1) * 4096, t);
    }
    const bf16_t* la = ldsA + cur * 4096;
    const bf16_t* lb = ldsB + cur * 4096;
    bf16x8 av[4], bv[4];
#pragma unroll
    for (int i = 0; i < 4; ++i)
      av[i] = *reinterpret_cast<const bf16x8*>(la + (wr + i * 16 + rr) * 32 + qs);
#pragma unroll
    for (int i = 0; i < 4; ++i)
      bv[i] = *reinterpret_cast<const bf16x8*>(lb + (wc + i * 16 + rr) * 32 + qs);
#pragma unroll
    for (int i = 0; i < 4; ++i)
#pragma unroll
      for (int j = 0; j < 4; ++j)
        acc[i][j] = __builtin_amdgcn_mfma_f32_16x16x32_bf16(av[i], bv[j], acc[i][j], 0, 0, 0);
    cur ^= 1;
  }
  __syncthreads();
}

// ------------------------------------------------- generic bias(+relu) GEMM
template<int KS, bool RELU, bool OUTF32>
__global__ __launch_bounds__(256, 4) void k_gemm_bias(
    const bf16_t* __restrict__ A, int lda,
    const bf16_t* __restrict__ Bt, int ldb,
    const bf16_t* __restrict__ bias, int nbias,
    void* __restrict__ outv, int ldo, int nout,
    const int* __restrict__ layC)
{
  __shared__ bf16_t sAB[4 * 4096];
  const int lay = layC[0];
  const int t = threadIdx.x;
  const int w = t >> 6, lane = t & 63;
  const int rr = lane & 15, qq = lane >> 4;
  const int wr = (w >> 1) * 64, wc = (w & 1) * 64;
  const int rowT = blockIdx.x * 128, colT = blockIdx.y * 128;
  f32x4 acc[4][4]; acc_zero(acc);
  gemm_staged<KS>(A + (size_t)rowT * lda, lda, Bt + (size_t)colT * ldb, ldb,
                  sAB, sAB + 8192, wr, wc, rr, qq, t, acc);
  const int row0 = rowT + wr, col0 = colT + wc;
  float bjv[4];
#pragma unroll
  for (int j = 0; j < 4; ++j) {
    int c = col0 + j * 16 + rr;
    bjv[j] = (c < nbias) ? (float)bias[c] : 0.f;
  }
  if (lay == 0 && !OUTF32) {
    bf16_t* eld = sAB + w * 2304;     // 32 rows x stride 72
#pragma unroll
    for (int p = 0; p < 2; ++p) {
#pragma unroll
      for (int ii = 0; ii < 2; ++ii) {
        int i = p * 2 + ii;
#pragma unroll
        for (int j = 0; j < 4; ++j) {
#pragma unroll
          for (int e = 0; e < 4; ++e) {
            float v = acc[i][j][e] + bjv[j];
            if (RELU) v = fmaxf(v, 0.f);
            eld[(ii * 16 + qq * 4 + e) * 72 + j * 16 + rr] = (bf16_t)v;
          }
        }
      }
#pragma unroll
      for (int rb = 0; rb < 4; ++rb) {
        int rl = rb * 8 + (lane >> 3);
        int c8 = (lane & 7) * 8;
        bf16x8 vv = *reinterpret_cast<const bf16x8*>(eld + rl * 72 + c8);
        int row = row0 + p * 32 + rl;
        int col = colT + wc + c8;
        if (col < nout)
          *reinterpret_cast<bf16x8*>((bf16_t*)outv + (size_t)row * ldo + col) = vv;
      }
    }
  } else {
#pragma unroll
    for (int j = 0; j < 4; ++j) {
#pragma unroll
      for (int i = 0; i < 4; ++i) {
#pragma unroll
        for (int e = 0; e < 4; ++e) {
          int ri = lay ? rr : qq * 4 + e;
          int ci = lay ? qq * 4 + e : rr;
          int row = row0 + i * 16 + ri;
          int col = col0 + j * 16 + ci;
          if (col >= nout) continue;
          float bv = (col < nbias) ? (float)bias[col] : 0.f;
          float v = acc[i][j][e] + bv;
          if (RELU) v = fmaxf(v, 0.f);
          if (OUTF32) ((float*)outv)[(size_t)row * ldo + col] = v;
          else ((bf16_t*)outv)[(size_t)row * ldo + col] = (bf16_t)v;
        }
      }
    }
  }
}

// ---- merged front pair: z=0: out1=relu(x@W1+b1)  z=1: emb0=emb@em_w+em_b ----
__global__ __launch_bounds__(256, 4) void k_gemm_front_pair(
    const bf16_t* __restrict__ A0, const bf16_t* __restrict__ A1,
    const bf16_t* __restrict__ B0, const bf16_t* __restrict__ B1,
    const bf16_t* __restrict__ bias0, const bf16_t* __restrict__ bias1,
    bf16_t* __restrict__ o0, bf16_t* __restrict__ o1,
    const int* __restrict__ layC)
{
  __shared__ bf16_t sAB[4 * 4096];
  const int z = blockIdx.z;
  const bf16_t* A    = z ? A1 : A0;
  const bf16_t* Bt   = z ? B1 : B0;
  const bf16_t* bias = z ? bias1 : bias0;
  bf16_t* outv       = z ? o1 : o0;
  const int  ld   = z ? DEM_ : DIN_;   // lda == ldb for both
  const int  KS   = z ? 2 : 4;
  const bool relu = (z == 0);
  const int lay = layC[0];
  const int t = threadIdx.x;
  const int w = t >> 6, lane = t & 63;
  const int rr = lane & 15, qq = lane >> 4;
  const int wr = (w >> 1) * 64, wc = (w & 1) * 64;
  const int rowT = blockIdx.x * 128, colT = blockIdx.y * 128;
  f32x4 acc[4][4]; acc_zero(acc);
  gemm_staged_rt(A + (size_t)rowT * ld, ld, Bt + (size_t)colT * ld, ld,
                 sAB, sAB + 8192, wr, wc, rr, qq, t, KS, acc);
  const int row0 = rowT + wr, col0 = colT + wc;
  float bjv[4];
#pragma unroll
  for (int j = 0; j < 4; ++j) {
    int c = col0 + j * 16 + rr;
    bjv[j] = (c < DH_) ? (float)bias[c] : 0.f;
  }
  if (lay == 0) {
    bf16_t* eld = sAB + w * 2304;
#pragma unroll
    for (int p = 0; p < 2; ++p) {
#pragma unroll
      for (int ii = 0; ii < 2; ++ii) {
        int i = p * 2 + ii;
#pragma unroll
        for (int j = 0; j < 4; ++j) {
#pragma unroll
          for (int e = 0; e < 4; ++e) {
            float v = acc[i][j][e] + bjv[j];
            if (relu) v = fmaxf(v, 0.f);
            eld[(ii * 16 + qq * 4 + e) * 72 + j * 16 + rr] = (bf16_t)v;
          }
        }
      }
#pragma unroll
      for (int rb = 0; rb < 4; ++rb) {
        int rl = rb * 8 + (lane >> 3);
        int c8 = (lane & 7) * 8;
        bf16x8 vv = *reinterpret_cast<const bf16x8*>(eld + rl * 72 + c8);
        int row = row0 + p * 32 + rl;
        int col = colT + wc + c8;
        if (col < DHP_)
          *reinterpret_cast<bf16x8*>(outv + (size_t)row * DHP_ + col) = vv;
      }
    }
  } else {
#pragma unroll
    for (int j = 0; j < 4; ++j) {
#pragma unroll
      for (int i = 0; i < 4; ++i) {
#pragma unroll
        for (int e = 0; e < 4; ++e) {
          int row = row0 + i * 16 + rr;
          int col = col0 + j * 16 + qq * 4 + e;
          if (col >= DHP_) continue;
          float bv = (col < DH_) ? (float)bias[col] : 0.f;
          float v = acc[i][j][e] + bv;
          if (relu) v = fmaxf(v, 0.f);
          outv[(size_t)row * DHP_ + col] = (bf16_t)v;
        }
      }
    }
  }
}

// ---- base layer 2: outA=relu(A@W2+b2); emb1=relu(emb0*(A@W2+b2)); fused stats
__global__ __launch_bounds__(256, 4) void k_gemm_base2(
    const bf16_t* __restrict__ A, const bf16_t* __restrict__ Bt,
    const bf16_t* __restrict__ bias, const bf16_t* __restrict__ emb0,
    bf16_t* __restrict__ outA, bf16_t* __restrict__ emb1,
    float* __restrict__ ps, float* __restrict__ pq,
    const int* __restrict__ layC)
{
  __shared__ bf16_t sAB[4 * 4096];
  __shared__ float rs[2][128], rq[2][128];
  const int lay = layC[0];
  const int t = threadIdx.x;
  const int w = t >> 6, lane = t & 63;
  const int rr = lane & 15, qq = lane >> 4;
  const int wr = (w >> 1) * 64, wc = (w & 1) * 64;
  const int rowT = blockIdx.x * 128, colT = blockIdx.y * 128;
  f32x4 acc[4][4]; acc_zero(acc);
  gemm_staged<13>(A + (size_t)rowT * DHP_, DHP_, Bt + (size_t)colT * DHP_, DHP_,
                  sAB, sAB + 8192, wr, wc, rr, qq, t, acc);
  const int row0 = rowT + wr, col0 = colT + wc;
  float bjv[4];
  bool cok[4];
#pragma unroll
  for (int j = 0; j < 4; ++j) {
    int c = col0 + j * 16 + rr;
    bjv[j] = (c < DH_) ? (float)bias[c] : 0.f;
    cok[j] = (c < DHP_);
  }
  float s[4] = {0.f, 0.f, 0.f, 0.f}, q[4] = {0.f, 0.f, 0.f, 0.f};
  if (lay == 0) {
#pragma unroll
    for (int j = 0; j < 4; ++j) {
      if (!cok[j]) continue;
#pragma unroll
      for (int i = 0; i < 4; ++i)
#pragma unroll
        for (int e = 0; e < 4; ++e) {
          float o = fmaxf(acc[i][j][e] + bjv[j], 0.f);
          s[j] += o; q[j] += o * o;
        }
    }
    float* fld = reinterpret_cast<float*>(sAB) + w * 1088;   // 16 rows x 68 f32
#pragma unroll
    for (int i = 0; i < 4; ++i) {
#pragma unroll
      for (int j = 0; j < 4; ++j)
#pragma unroll
        for (int e = 0; e < 4; ++e)
          fld[(qq * 4 + e) * 68 + j * 16 + rr] = acc[i][j][e] + bjv[j];
#pragma unroll
      for (int rb = 0; rb < 4; ++rb) {
        int rl = rb * 4 + (lane >> 4);
        int c4 = (lane & 15) * 4;
        f32x4 op4 = *reinterpret_cast<const f32x4*>(fld + rl * 68 + c4);
        int row = row0 + i * 16 + rl;
        int col = colT + wc + c4;
        if (col < DHP_) {
          bf16x4 e04 = *reinterpret_cast<const bf16x4*>(emb0 + (size_t)row * DHP_ + col);
          bf16x4 oA4, e14;
#pragma unroll
          for (int e = 0; e < 4; ++e) {
            float op = op4[e];
            oA4[e] = (bf16_t)fmaxf(op, 0.f);
            e14[e] = (bf16_t)fmaxf((float)e04[e] * op, 0.f);
          }
          *reinterpret_cast<bf16x4*>(outA + (size_t)row * DHP_ + col) = oA4;
          *reinterpret_cast<bf16x4*>(emb1 + (size_t)row * DHP_ + col) = e14;
        }
      }
    }
  } else {
#pragma unroll
    for (int j = 0; j < 4; ++j) {
#pragma unroll
      for (int i = 0; i < 4; ++i) {
#pragma unroll
        for (int e = 0; e < 4; ++e) {
          int ri = rr;
          int ci = qq * 4 + e;
          int row = row0 + i * 16 + ri;
          int col = col0 + j * 16 + ci;
          if (col >= DHP_) continue;
          float bv = (col < DH_) ? (float)bias[col] : 0.f;
          float op = acc[i][j][e] + bv;
          float o  = fmaxf(op, 0.f);
          float e0 = (float)emb0[(size_t)row * DHP_ + col];
          float m1 = fmaxf(e0 * op, 0.f);
          outA[(size_t)row * DHP_ + col] = (bf16_t)o;
          emb1[(size_t)row * DHP_ + col] = (bf16_t)m1;
        }
      }
    }
  }
#pragma unroll
  for (int j = 0; j < 4; ++j) {
    s[j] += __shfl_xor(s[j], 16); s[j] += __shfl_xor(s[j], 32);
    q[j] += __shfl_xor(q[j], 16); q[j] += __shfl_xor(q[j], 32);
  }
  if (lane < 16) {
#pragma unroll
    for (int j = 0; j < 4; ++j) {
      rs[w >> 1][(w & 1) * 64 + j * 16 + lane] = s[j];
      rq[w >> 1][(w & 1) * 64 + j * 16 + lane] = q[j];
    }
  }
  __syncthreads();
  if (lay == 0 && t < 128) {
    int col = blockIdx.y * 128 + t;
    if (col < PCOLS) {
      ps[((size_t)blockIdx.x * MM_ + 0) * PCOLS + col] = rs[0][t] + rs[1][t];
      pq[((size_t)blockIdx.x * MM_ + 0) * PCOLS + col] = rq[0][t] + rq[1][t];
    }
  }
}

// ---- module GEMM: mo[b][m][:] = A_m[b][:] @ W'_m + b'_m; fused mo stats
__global__ __launch_bounds__(256, 4) void k_gemm_mod(
    const bf16_t* __restrict__ Abase, int lda, int mstride,
    const bf16_t* __restrict__ WtM, const float* __restrict__ bM,
    bf16_t* __restrict__ mo,
    float* __restrict__ ps, float* __restrict__ pq,
    const int* __restrict__ layC)
{
  __shared__ bf16_t sAB[4 * 4096];
  __shared__ float rs[2][128], rq[2][128];
  const int lay = layC[0];
  const int m = blockIdx.z;
  const int t = threadIdx.x;
  const int w = t >> 6, lane = t & 63;
  const int rr = lane & 15, qq = lane >> 4;
  const int wr = (w >> 1) * 64, wc = (w & 1) * 64;
  const int rowT = blockIdx.x * 128, colT = blockIdx.y * 128;
  f32x4 acc[4][4]; acc_zero(acc);
  gemm_staged<13>(Abase + (size_t)m * mstride + (size_t)rowT * lda, lda,
                  WtM + (size_t)m * DHA_ * DHP_ + (size_t)colT * DHP_, DHP_,
                  sAB, sAB + 8192, wr, wc, rr, qq, t, acc);
  const int row0 = rowT + wr, col0 = colT + wc;
  float bjv[4];
  bool cok[4];
#pragma unroll
  for (int j = 0; j < 4; ++j) {
    int c = col0 + j * 16 + rr;
    bjv[j] = bM[m * DHA_ + c];
    cok[j] = (c < DHP_);
  }
  float s[4] = {0.f, 0.f, 0.f, 0.f}, q[4] = {0.f, 0.f, 0.f, 0.f};
  if (lay == 0) {
#pragma unroll
    for (int j = 0; j < 4; ++j) {
      if (!cok[j]) continue;
#pragma unroll
      for (int i = 0; i < 4; ++i)
#pragma unroll
        for (int e = 0; e < 4; ++e) {
          float v = acc[i][j][e] + bjv[j];
          s[j] += v; q[j] += v * v;
        }
    }
    bf16_t* eld = sAB + w * 2304;     // 32 rows x stride 72
#pragma unroll
    for (int p = 0; p < 2; ++p) {
#pragma unroll
      for (int ii = 0; ii < 2; ++ii) {
        int i = p * 2 + ii;
#pragma unroll
        for (int j = 0; j < 4; ++j)
#pragma unroll
          for (int e = 0; e < 4; ++e)
            eld[(ii * 16 + qq * 4 + e) * 72 + j * 16 + rr] = (bf16_t)(acc[i][j][e] + bjv[j]);
      }
#pragma unroll
      for (int rb = 0; rb < 4; ++rb) {
        int rl = rb * 8 + (lane >> 3);
        int c8 = (lane & 7) * 8;
        bf16x8 vv = *reinterpret_cast<const bf16x8*>(eld + rl * 72 + c8);
        int row = row0 + p * 32 + rl;
        int col = colT + wc + c8;
        if (col < DHP_)
          *reinterpret_cast<bf16x8*>(mo + ((size_t)row * MM_ + m) * DHP_ + col) = vv;
      }
    }
  } else {
#pragma unroll
    for (int j = 0; j < 4; ++j) {
#pragma unroll
      for (int i = 0; i < 4; ++i) {
#pragma unroll
        for (int e = 0; e < 4; ++e) {
          int row = row0 + i * 16 + rr;
          int col = col0 + j * 16 + qq * 4 + e;
          if (col >= DHP_) continue;
          float v = acc[i][j][e] + bM[m * DHA_ + col];
          mo[((size_t)row * MM_ + m) * DHP_ + col] = (bf16_t)v;
        }
      }
    }
  }
#pragma unroll
  for (int j = 0; j < 4; ++j) {
    s[j] += __shfl_xor(s[j], 16); s[j] += __shfl_xor(s[j], 32);
    q[j] += __shfl_xor(q[j], 16); q[j] += __shfl_xor(q[j], 32);
  }
  if (lane < 16) {
#pragma unroll
    for (int j = 0; j < 4; ++j) {
      rs[w >> 1][(w & 1) * 64 + j * 16 + lane] = s[j];
      rq[w >> 1][(w & 1) * 64 + j * 16 + lane] = q[j];
    }
  }
  __syncthreads();
  if (lay == 0 && t < 128) {
    int col = blockIdx.y * 128 + t;
    if (col < PCOLS) {
      ps[((size_t)blockIdx.x * MM_ + m) * PCOLS + col] = rs[0][t] + rs[1][t];
      pq[((size_t)blockIdx.x * MM_ + m) * PCOLS + col] = rq[0][t] + rq[1][t];
    }
  }
}

// ---------------- partials -> BN scale/shift (parallel, unrolled) ------------
template<int NCHT>
__global__ __launch_bounds__(512) void k_bnprep2(
    const float* __restrict__ ps, const float* __restrict__ pq, int per_m,
    const bf16_t* __restrict__ g, const bf16_t* __restrict__ b,
    float* __restrict__ s_o, float* __restrict__ t_o)
{
  __shared__ float lS[8][64], lQ[8][64];
  const int m = blockIdx.x, cg = blockIdx.y;
  const int sub = threadIdx.x >> 6, lane = threadIdx.x & 63;
  const int k = cg * 64 + lane;
  const int mm = per_m ? m : 0;
  float S = 0.f, Q = 0.f;
#pragma unroll 8
  for (int ch = sub; ch < NCHT; ch += 8) {
    size_t idx = ((size_t)ch * MM_ + mm) * PCOLS + k;
    S += ps[idx];
    Q += pq[idx];
  }
  lS[sub][lane] = S; lQ[sub][lane] = Q;
  __syncthreads();
  if (sub == 0 && k < DHP_) {
    float St = 0.f, Qt = 0.f;
#pragma unroll
    for (int i = 0; i < 8; ++i) { St += lS[i][lane]; Qt += lQ[i][lane]; }
    float s = 0.f, t = 0.f;
    if (k < DH_) {
      float mean = St * (1.f / BN_);
      float var  = fmaxf(Qt * (1.f / BN_) - mean * mean, 0.f);
      float rstd = rsqrtf(var + EPS_);
      s = (float)g[m * DH_ + k] * rstd;
      t = (float)b[m * DH_ + k] - mean * s;
    }
    s_o[m * DHP_ + k] = s;
    t_o[m * DHP_ + k] = t;
  }
}

// ---------------- routing mix + fused BN1 stats of mi ------------------------
__global__ __launch_bounds__(256) void k_mix(
    const bf16_t* __restrict__ mo, const float* __restrict__ s2v, const float* __restrict__ t2v,
    const float* __restrict__ wbuf, int woff, bf16_t* __restrict__ mi,
    float* __restrict__ ps, float* __restrict__ pq)
{
  __shared__ float sB[4 * 416], qB[4 * 416];
  const int ch = blockIdx.x;
  const int wave = threadIdx.x >> 6, lane = threadIdx.x & 63;
  const int d0 = lane * 8;
  float sx[4][8], tx[4][8];
  float sAcc[4][8], qAcc[4][8];
#pragma unroll
  for (int j = 0; j < 4; ++j)
#pragma unroll
    for (int e = 0; e < 8; ++e) { sAcc[j][e] = 0.f; qAcc[j][e] = 0.f; }
  if (lane < 52) {
#pragma unroll
    for (int k = 0; k < 4; ++k)
#pragma unroll
      for (int e = 0; e < 8; ++e) {
        sx[k][e] = s2v[k * DHP_ + d0 + e];
        tx[k][e] = t2v[k * DHP_ + d0 + e];
      }
  }
#pragma unroll 1
  for (int i = 0; i < 16; ++i) {
    int b = ch * 64 + wave + i * 4;
    float wv = (lane < 16) ? wbuf[(size_t)b * 52 + woff + lane] : 0.f;
    if (lane < 52) {
      float x[4][8];
#pragma unroll
      for (int k = 0; k < 4; ++k) {
        bf16x8 v = *reinterpret_cast<const bf16x8*>(mo + ((size_t)b * MM_ + k) * DHP_ + d0);
#pragma unroll
        for (int e = 0; e < 8; ++e)
          x[k][e] = (float)v[e] * sx[k][e] + tx[k][e];
      }
#pragma unroll
      for (int j = 0; j < 4; ++j) {
        float w0 = __shfl(wv, j * 4 + 0), w1 = __shfl(wv, j * 4 + 1);
        float w2 = __shfl(wv, j * 4 + 2), w3 = __shfl(wv, j * 4 + 3);
        bf16x8 ov;
#pragma unroll
        for (int e = 0; e < 8; ++e) {
          float a = fmaxf(x[0][e] * w0 + x[1][e] * w1 + x[2][e] * w2 + x[3][e] * w3, 0.f);
          ov[e] = (bf16_t)a;
          float r = (float)ov[e];          // stats of the stored (rounded) value
          sAcc[j][e] += r; qAcc[j][e] += r * r;
        }
        *reinterpret_cast<bf16x8*>(mi + ((size_t)b * MM_ + j) * DHP_ + d0) = ov;
      }
    }
  }
  // deterministic cross-wave reduce
#pragma unroll 1
  for (int w = 0; w < 4; ++w) {
    if (wave == w && lane < 52) {
#pragma unroll
      for (int j = 0; j < 4; ++j)
#pragma unroll
        for (int e = 0; e < 8; ++e) {
          int idx = j * 416 + d0 + e;
          if (w == 0) { sB[idx] = sAcc[j][e]; qB[idx] = qAcc[j][e]; }
          else        { sB[idx] += sAcc[j][e]; qB[idx] += qAcc[j][e]; }
        }
    }
    __syncthreads();
  }
  for (int idx = threadIdx.x; idx < 4 * 416; idx += 256) {
    int j = idx / 416, col = idx - j * 416;
    ps[((size_t)ch * MM_ + j) * PCOLS + col] = sB[idx];
    pq[((size_t)ch * MM_ + j) * PCOLS + col] = qB[idx];
  }
}

// ------------- gating cascade v5 (measured-best): 4 indep waves/block, 2 samp/wave
__global__ __launch_bounds__(256) void k_gate(
    const bf16_t* __restrict__ emb,
    const bf16_t* __restrict__ gw0t, const bf16_t* __restrict__ gw0_b,
    const bf16_t* __restrict__ c1_w,  const bf16_t* __restrict__ c1_b,
    const bf16_t* __restrict__ gw1t, const bf16_t* __restrict__ gw1_b,
    const bf16_t* __restrict__ c2_w,  const bf16_t* __restrict__ c2_b,
    const bf16_t* __restrict__ gw2t, const bf16_t* __restrict__ gw2_b,
    const bf16_t* __restrict__ cL_w,  const bf16_t* __restrict__ cL_b,
    const bf16_t* __restrict__ gwLt, const bf16_t* __restrict__ gwL_b,
    float* __restrict__ wbuf)
{
  __shared__ float VBA[4][272], VBB[4][272];
  __shared__ float FLA[4][64], FLB[4][64];
  const int wave = threadIdx.x >> 6, lane = threadIdx.x & 63;
  float* vbA = VBA[wave];
  float* vbB = VBB[wave];
  float* flA = FLA[wave];
  float* flB = FLB[wave];
  const int bA = blockIdx.x * 8 + wave * 2, bB = bA + 1;
  const int wrIdx = lane * 4 + (lane >> 4) * 4;

  float eA[4], eB[4];
  {
    bf16x4 evA = *reinterpret_cast<const bf16x4*>(emb + (size_t)bA * GH_ + lane * 4);
    bf16x4 evB = *reinterpret_cast<const bf16x4*>(emb + (size_t)bB * GH_ + lane * 4);
    f32x4 rA, rB;
#pragma unroll
    for (int e = 0; e < 4; ++e) {
      eA[e] = (float)evA[e]; rA[e] = fmaxf(eA[e], 0.f);
      eB[e] = (float)evB[e]; rB[e] = fmaxf(eB[e], 0.f);
    }
    *reinterpret_cast<f32x4*>(vbA + wrIdx) = rA;
    *reinterpret_cast<f32x4*>(vbB + wrIdx) = rB;
  }
  __builtin_amdgcn_wave_barrier();

  const int hh = lane >> 4, jj = lane & 15;

  auto softmax4 = [&](float a) -> float {
    float m1 = fmaxf(a, __shfl_xor(a, 1));
    float mx = fmaxf(m1, __shfl_xor(m1, 2));
    float ex = __expf(a - mx);
    float sx = ex + __shfl_xor(ex, 1);
    float sm = sx + __shfl_xor(sx, 2);
    return ex / sm;
  };

  auto gw_phase = [&](const bf16_t* Wt, const bf16_t* Bb, int foff) {
    float a0A = 0.f, a1A = 0.f, a0B = 0.f, a1B = 0.f;
#pragma unroll
    for (int cc = 0; cc < 8; ++cc) {
      int c8 = (cc + hh * 2) & 7;
      int k  = hh * 64 + c8 * 8;
      int idx = k + hh * 4;
      f32x4 vA0 = *reinterpret_cast<const f32x4*>(vbA + idx);
      f32x4 vA1 = *reinterpret_cast<const f32x4*>(vbA + idx + 4);
      f32x4 vB0 = *reinterpret_cast<const f32x4*>(vbB + idx);
      f32x4 vB1 = *reinterpret_cast<const f32x4*>(vbB + idx + 4);
      bf16x8 wv = *reinterpret_cast<const bf16x8*>(Wt + jj * 256 + k);
      float w0 = (float)wv[0], w1 = (float)wv[1], w2 = (float)wv[2], w3 = (float)wv[3];
      float w4 = (float)wv[4], w5 = (float)wv[5], w6 = (float)wv[6], w7 = (float)wv[7];
      a0A = fmaf(vA0[0], w0, a0A); a0A = fmaf(vA0[1], w1, a0A);
      a0A = fmaf(vA0[2], w2, a0A); a0A = fmaf(vA0[3], w3, a0A);
      a1A = fmaf(vA1[0], w4, a1A); a1A = fmaf(vA1[1], w5, a1A);
      a1A = fmaf(vA1[2], w6, a1A); a1A = fmaf(vA1[3], w7, a1A);
      a0B = fmaf(vB0[0], w0, a0B); a0B = fmaf(vB0[1], w1, a0B);
      a0B = fmaf(vB0[2], w2, a0B); a0B = fmaf(vB0[3], w3, a0B);
      a1B = fmaf(vB1[0], w4, a1B); a1B = fmaf(vB1[1], w5, a1B);
      a1B = fmaf(vB1[2], w6, a1B); a1B = fmaf(vB1[3], w7, a1B);
    }
    float aA = a0A + a1A, aB = a0B + a1B;
    aA += __shfl_xor(aA, 16); aA += __shfl_xor(aA, 32);
    aB += __shfl_xor(aB, 16); aB += __shfl_xor(aB, 32);
    float bb = (float)Bb[jj];
    aA += bb; aB += bb;
    float wA = softmax4(aA), wB = softmax4(aB);
    if (lane < 16) {
      flA[foff + jj] = wA; wbuf[(size_t)bA * 52 + foff + jj] = wA;
      flB[foff + jj] = wB; wbuf[(size_t)bB * 52 + foff + jj] = wB;
    }
    __builtin_amdgcn_wave_barrier();
  };

  auto cond_phase = [&](const bf16_t* W, const bf16_t* Bb, int tcount) {
    float a4A[4], a4B[4];
    bf16x4 bb = *reinterpret_cast<const bf16x4*>(Bb + lane * 4);
#pragma unroll
    for (int e = 0; e < 4; ++e) { a4A[e] = (float)bb[e]; a4B[e] = a4A[e]; }
    for (int t = 0; t < tcount; ++t) {
      float fA = flA[t], fB = flB[t];
      bf16x4 wv = *reinterpret_cast<const bf16x4*>(W + t * 256 + lane * 4);
#pragma unroll
      for (int e = 0; e < 4; ++e) {
        float w = (float)wv[e];
        a4A[e] = fmaf(fA, w, a4A[e]);
        a4B[e] = fmaf(fB, w, a4B[e]);
      }
    }
    f32x4 rA, rB;
#pragma unroll
    for (int e = 0; e < 4; ++e) {
      rA[e] = fmaxf(a4A[e] * eA[e], 0.f);
      rB[e] = fmaxf(a4B[e] * eB[e], 0.f);
    }
    *reinterpret_cast<f32x4*>(vbA + wrIdx) = rA;
    *reinterpret_cast<f32x4*>(vbB + wrIdx) = rB;
    __builtin_amdgcn_wave_barrier();
  };

  gw_phase(gw0t, gw0_b, 0);
  cond_phase(c1_w, c1_b, 16);
  gw_phase(gw1t, gw1_b, 16);
  cond_phase(c2_w, c2_b, 32);
  gw_phase(gw2t, gw2_b, 32);
  cond_phase(cL_w, cL_b, 48);
  {
    const int j4 = lane & 3, h16 = lane >> 2;
    const int base = h16 * 16 + (h16 >> 2) * 4;
    bf16x8 w0 = *reinterpret_cast<const bf16x8*>(gwLt + j4 * 256 + h16 * 16);
    bf16x8 w1 = *reinterpret_cast<const bf16x8*>(gwLt + j4 * 256 + h16 * 16 + 8);
    float aA = 0.f, aB = 0.f;
#pragma unroll
    for (int c = 0; c < 2; ++c) {
      f32x4 vA0 = *reinterpret_cast<const f32x4*>(vbA + base + c * 8);
      f32x4 vA1 = *reinterpret_cast<const f32x4*>(vbA + base + c * 8 + 4);
      f32x4 vB0 = *reinterpret_cast<const f32x4*>(vbB + base + c * 8);
      f32x4 vB1 = *reinterpret_cast<const f32x4*>(vbB + base + c * 8 + 4);
      const bf16x8& w = c ? w1 : w0;
#pragma unroll
      for (int e = 0; e < 4; ++e) {
        aA = fmaf(vA0[e], (float)w[e], aA);
        aA = fmaf(vA1[e], (float)w[e + 4], aA);
        aB = fmaf(vB0[e], (float)w[e], aB);
        aB = fmaf(vB1[e], (float)w[e + 4], aB);
      }
    }
    aA += __shfl_xor(aA, 4); aA += __shfl_xor(aA, 8);
    aA += __shfl_xor(aA, 16); aA += __shfl_xor(aA, 32);
    aB += __shfl_xor(aB, 4); aB += __shfl_xor(aB, 8);
    aB += __shfl_xor(aB, 16); aB += __shfl_xor(aB, 32);
    float bb = (float)gwL_b[j4];
    aA += bb; aB += bb;
    float wA = softmax4(aA), wB = softmax4(aB);
    if (lane < 4) {
      wbuf[(size_t)bA * 52 + 48 + j4] = wA;
      wbuf[(size_t)bB * 52 + 48 + j4] = wB;
    }
  }
}

// ------------- final: BN2-affine, last_weight mix, relu, @last_w + last_b ----
__global__ __launch_bounds__(256) void k_final(
    const bf16_t* __restrict__ mo, const float* __restrict__ s2v, const float* __restrict__ t2v,
    const float* __restrict__ wbuf, const bf16_t* __restrict__ last_w,
    const bf16_t* __restrict__ last_b, void* __restrict__ outv,
    const int* __restrict__ flag)
{
  const int f32out = flag[0];
  const int wave = threadIdx.x >> 6, lane = threadIdx.x & 63;
  const int d0 = lane * 8;
  float sx[4][8], tx[4][8];
  if (lane < 52) {
#pragma unroll
    for (int k = 0; k < 4; ++k)
#pragma unroll
      for (int e = 0; e < 8; ++e) {
        sx[k][e] = s2v[k * DHP_ + d0 + e];
        tx[k][e] = t2v[k * DHP_ + d0 + e];
      }
  }
  for (int b = blockIdx.x * 4 + wave; b < BN_; b += gridDim.x * 4) {
    const float* lwp = wbuf + (size_t)b * 52 + 48;
    float lm0 = lwp[0], lm1 = lwp[1], lm2 = lwp[2], lm3 = lwp[3];
    float slm = lm0 + lm1 + lm2 + lm3;
    const float* w0p = wbuf + (size_t)b * 52;
    float sw0 = w0p[0] + w0p[1] + w0p[2] + w0p[3];
    float p[8];
#pragma unroll
    for (int j = 0; j < 8; ++j) p[j] = 0.f;
    if (lane < 52) {
      float x[4][8];
#pragma unroll
      for (int k = 0; k < 4; ++k) {
        bf16x8 v = *reinterpret_cast<const bf16x8*>(mo + ((size_t)b * MM_ + k) * DHP_ + d0);
#pragma unroll
        for (int e = 0; e < 8; ++e)
          x[k][e] = (float)v[e] * sx[k][e] + tx[k][e];
      }
#pragma unroll
      for (int e = 0; e < 8; ++e) {
        float v = fmaxf(x[0][e] * lm0 + x[1][e] * lm1 + x[2][e] * lm2 + x[3][e] * lm3, 0.f);
        bf16x8 wv = *reinterpret_cast<const bf16x8*>(last_w + (size_t)(d0 + e) * 8);
#pragma unroll
        for (int j = 0; j < 8; ++j) p[j] = fmaf(v, (float)wv[j], p[j]);
      }
    }
#pragma unroll
    for (int j = 0; j < 8; ++j) {
      p[j] += __shfl_xor(p[j], 1);
      p[j] += __shfl_xor(p[j], 2);
      p[j] += __shfl_xor(p[j], 4);
      p[j] += __shfl_xor(p[j], 8);
      p[j] += __shfl_xor(p[j], 16);
      p[j] += __shfl_xor(p[j], 32);
    }
    float sel = p[0];
#pragma unroll
    for (int j = 1; j < 8; ++j) if (lane == j) sel = p[j];
    if (lane < 8) {
      float res = sel + (float)last_b[lane];
      if (!(fabsf(res) < 1e4f)) res = 400.f;
      if (!(slm > 0.97f && slm < 1.03f)) res = 1000.f;
      if (!(sw0 > 0.97f && sw0 < 1.03f)) res = 2000.f;
      if (f32out) ((float*)outv)[(size_t)b * 8 + lane] = res;
      else ((bf16_t*)outv)[(size_t)b * 8 + lane] = (bf16_t)res;
    }
  }
}

// ======================================================================
extern "C" void kernel_launch(void* const* d_in, const int* in_sizes, int n_in,
                              void* d_out, int out_size, void* d_ws, size_t ws_size,
                              hipStream_t stream)
{
  (void)in_sizes; (void)n_in;
  const void* x_raw   = d_in[0];
  const void* emb_raw = d_in[1];
  const void* base_w1 = d_in[2];
  const void* base_w2 = d_in[4];
  const void* em_w    = d_in[6];
  const void* gfc_w1  = d_in[8];
  const void* gfc_w2  = d_in[10];
  const void* modW_raw= d_in[28];

  char* base = (char*)d_ws;
  size_t off = 0;
  auto alloc = [&](size_t bytes) -> char* {
    off = (off + 255) & ~(size_t)255;
    char* r = base + off; off += bytes; return r;
  };
  int*    dflag = (int*)   alloc(16);
  int*    layC  = (int*)   alloc(16);
  bf16_t* Wt1  = (bf16_t*)alloc((size_t)512 * 128 * 2);
  bf16_t* Wem  = (bf16_t*)alloc((size_t)512 * 64 * 2);
  bf16_t* Wt2  = (bf16_t*)alloc((size_t)512 * DHP_ * 2);
  bf16_t* Wg1  = (bf16_t*)alloc((size_t)256 * DHP_ * 2);
  bf16_t* Wg2  = (bf16_t*)alloc((size_t)256 * 256 * 2);
  bf16_t* WtM  = (bf16_t*)alloc((size_t)MM_ * DHA_ * DHP_ * 2);
  float*  bM   = (float*) alloc((size_t)MM_ * DHA_ * 4);
  bf16_t* xc   = (bf16_t*)alloc((size_t)BN_ * DIN_ * 2);
  bf16_t* embc = (bf16_t*)alloc((size_t)BN_ * DEM_ * 2);
  bf16_t* out1 = (bf16_t*)alloc((size_t)BN_ * DHP_ * 2);
  bf16_t* emb0 = (bf16_t*)alloc((size_t)BN_ * DHP_ * 2);
  bf16_t* outA = (bf16_t*)alloc((size_t)BN_ * DHP_ * 2);
  bf16_t* emb1 = (bf16_t*)alloc((size_t)BN_ * DHP_ * 2);
  bf16_t* embF = (bf16_t*)alloc((size_t)BN_ * GH_ * 2);
  float*  wbuf = (float*) alloc((size_t)BN_ * 52 * 4);
  bf16_t* mo   = (bf16_t*)alloc((size_t)BN_ * MM_ * DHP_ * 2);
  bf16_t* mi   = (bf16_t*)alloc((size_t)BN_ * MM_ * DHP_ * 2);
  float* psO = (float*)alloc((size_t)NCH * MM_ * PCOLS * 4);
  float* pqO = (float*)alloc((size_t)NCH * MM_ * PCOLS * 4);
  float* psA = (float*)alloc((size_t)NCHMI * MM_ * PCOLS * 4);
  float* pqA = (float*)alloc((size_t)NCHMI * MM_ * PCOLS * 4);
  float* psB = (float*)alloc((size_t)NCH * MM_ * PCOLS * 4);
  float* pqB = (float*)alloc((size_t)NCH * MM_ * PCOLS * 4);
  float* s1 = (float*)alloc((size_t)MM_ * DHP_ * 4);
  float* t1 = (float*)alloc((size_t)MM_ * DHP_ * 4);
  float* s2 = (float*)alloc((size_t)MM_ * DHP_ * 4);
  float* t2 = (float*)alloc((size_t)MM_ * DHP_ * 4);
  bf16_t* gw0t = (bf16_t*)alloc((size_t)16 * 256 * 2);
  bf16_t* gw1t = (bf16_t*)alloc((size_t)16 * 256 * 2);
  bf16_t* gw2t = (bf16_t*)alloc((size_t)16 * 256 * 2);
  bf16_t* gwLt = (bf16_t*)alloc((size_t)4 * 256 * 2);
  const int sn[NS_] = {400, 400, 400, 256, 256,
                       4096, 16, 4096, 256, 4096, 16, 8192, 256, 4096, 16,
                       12288, 256, 1024, 4,
                       6400, 6400, 6400, 6400, 6400, 3200, 8};
  const int si[NS_] = {3, 5, 7, 9, 11,
                       12, 13, 14, 15, 16, 17, 18, 19, 20, 21,
                       22, 23, 24, 25,
                       26, 27, 29, 30, 31, 32, 33};
  bf16_t* sc[NS_];
  for (int i = 0; i < NS_; ++i) sc[i] = (bf16_t*)alloc((size_t)sn[i] * 2);
  bf16_t *b1c = sc[0], *b2c = sc[1], *embbc = sc[2], *g1bc = sc[3], *g2bc = sc[4];
  bf16_t *gw0b = sc[6], *c1w = sc[7], *c1b = sc[8],
         *gw1b = sc[10], *c2w = sc[11], *c2b = sc[12], *gw2b = sc[14],
         *cLw = sc[15], *cLb = sc[16], *gwLb = sc[18];
  bf16_t *bn1g = sc[19], *bn1b = sc[20], *modbc = sc[21], *bn2g = sc[22], *bn2b = sc[23];
  bf16_t *lastw = sc[24], *lastb = sc[25];

  if (off > ws_size) {
    hipMemsetAsync(d_out, 0, (size_t)out_size * 2, stream);
    return;
  }

  dim3 blk(256);
  k_detect_probe<<<1, blk, 0, stream>>>((const unsigned*)x_raw, dflag, layC);

  // all transposes + ALL conversions in ONE dispatch
  SmallTab tab;
  for (int i = 0; i < NS_; ++i) { tab.src[i] = d_in[si[i]]; tab.dst[i] = sc[i]; tab.n[i] = sn[i]; }
  Cvt2 cv;
  cv.src1 = x_raw;   cv.dst1 = xc;   cv.n1 = BN_ * DIN_;
  cv.src2 = emb_raw; cv.dst2 = embc; cv.n2 = BN_ * DEM_;
  TransTab tt;
  tt.src[0] = base_w1;  tt.dst[0] = Wt1;  tt.K[0] = DIN_; tt.N[0] = DH_; tt.KP[0] = 128;  tt.NPa[0] = 512; tt.usef[0] = 1;
  tt.src[1] = em_w;     tt.dst[1] = Wem;  tt.K[1] = DEM_; tt.N[1] = DH_; tt.KP[1] = 64;   tt.NPa[1] = 512; tt.usef[1] = 1;
  tt.src[2] = base_w2;  tt.dst[2] = Wt2;  tt.K[2] = DH_;  tt.N[2] = DH_; tt.KP[2] = DHP_; tt.NPa[2] = 512; tt.usef[2] = 1;
  tt.src[3] = gfc_w1;   tt.dst[3] = Wg1;  tt.K[3] = DH_;  tt.N[3] = GH_; tt.KP[3] = DHP_; tt.NPa[3] = 256; tt.usef[3] = 1;
  tt.src[4] = gfc_w2;   tt.dst[4] = Wg2;  tt.K[4] = GH_;  tt.N[4] = GH_; tt.KP[4] = 256;  tt.NPa[4] = 256; tt.usef[4] = 1;
  tt.src[5] = d_in[12]; tt.dst[5] = gw0t; tt.K[5] = 256;  tt.N[5] = 16;  tt.KP[5] = 256;  tt.NPa[5] = 16;  tt.usef[5] = 1;
  tt.src[6] = d_in[16]; tt.dst[6] = gw1t; tt.K[6] = 256;  tt.N[6] = 16;  tt.KP[6] = 256;  tt.NPa[6] = 16;  tt.usef[6] = 1;
  tt.src[7] = d_in[20]; tt.dst[7] = gw2t; tt.K[7] = 256;  tt.N[7] = 16;  tt.KP[7] = 256;  tt.NPa[7] = 16;  tt.usef[7] = 1;
  tt.src[8] = d_in[24]; tt.dst[8] = gwLt; tt.K[8] = 256;  tt.N[8] = 4;   tt.KP[8] = 256;  tt.NPa[8] = 4;   tt.usef[8] = 1;
  k_transAll<<<dim3(7, 8, NT_ + 1 + CVZ), blk, 0, stream>>>(tt, tab, cv, dflag);

  // front MLPs: the two independent input GEMMs fused into one dispatch
  k_gemm_front_pair<<<dim3(128, 4, 2), blk, 0, stream>>>(
      xc, embc, Wt1, Wem, b1c, embbc, out1, emb0, layC);
  k_gemm_base2<<<dim3(128, 4), blk, 0, stream>>>(out1, Wt2, b2c, emb0, outA, emb1, psO, pqO, layC);
  bf16_t* emb2 = emb0;  // emb0 dead after base2 -> reuse
  k_gemm_bias<13, true , false><<<dim3(128, 2), blk, 0, stream>>>(emb1, DHP_, Wg1, DHP_, g1bc, GH_, emb2, GH_, GH_, layC);
  k_gemm_bias<8,  false, false><<<dim3(128, 2), blk, 0, stream>>>(emb2, GH_, Wg2, GH_, g2bc, GH_, embF, GH_, GH_, layC);

  // gating cascade (4 indep waves/block, 2 samples/wave — measured best)
  k_gate<<<dim3(BN_ / 8), blk, 0, stream>>>(embF,
      gw0t, gw0b, c1w, c1b, gw1t, gw1b, c2w, c2b, gw2t, gw2b,
      cLw, cLb, gwLt, gwLb, wbuf);

  // layer 0
  k_bnprep2<NCH><<<dim3(4, 7), dim3(512), 0, stream>>>(psO, pqO, 0, bn1g, bn1b, s1, t1);
  k_prepW<<<dim3(7, 9, 4), blk, 0, stream>>>(modW_raw, 0, modbc, s1, t1, WtM, bM, dflag);
  k_gemm_mod<<<dim3(128, 4, 4), blk, 0, stream>>>(outA, DHP_, 0, WtM, bM, mo, psB, pqB, layC);

  // layers 1..3
  for (int L = 1; L < 4; ++L) {
    k_bnprep2<NCH><<<dim3(4, 7), dim3(512), 0, stream>>>(psB, pqB, 1,
        bn2g + (size_t)(L - 1) * MM_ * DH_, bn2b + (size_t)(L - 1) * MM_ * DH_, s2, t2);
    k_mix<<<dim3(NCHMI), blk, 0, stream>>>(mo, s2, t2, wbuf, (L - 1) * 16, mi, psA, pqA);
    k_bnprep2<NCHMI><<<dim3(4, 7), dim3(512), 0, stream>>>(psA, pqA, 1,
        bn1g + (size_t)L * MM_ * DH_, bn1b + (size_t)L * MM_ * DH_, s1, t1);
    k_prepW<<<dim3(7, 9, 4), blk, 0, stream>>>(modW_raw, (size_t)L * MM_ * DH_ * DH_,
                                               modbc + (size_t)L * MM_ * DH_, s1, t1, WtM, bM, dflag);
    k_gemm_mod<<<dim3(128, 4, 4), blk, 0, stream>>>(mi, MM_ * DHP_, DHP_, WtM, bM, mo, psB, pqB, layC);
  }

  // final
  k_bnprep2<NCH><<<dim3(4, 7), dim3(512), 0, stream>>>(psB, pqB, 1,
      bn2g + (size_t)3 * MM_ * DH_, bn2b + (size_t)3 * MM_ * DH_, s2, t2);
  k_final<<<dim3(1024), blk, 0, stream>>>(mo, s2, t2, wbuf, lastw, lastb, d_out, dflag);
}